// Round 11
// baseline (728.940 us; speedup 1.0000x reference)
//
#include <hip/hip_runtime.h>

// ---------------------------------------------------------------------------
// VGG16-3D forward. R10: R9 + ring-2 z-half-slab pipeline for conv2/3/4:
// window k computes half-tile Hk from buf[k&1] while prefetching Hk+1 into
// registers (early) and ds-writing it to buf[(k+1)&1] (late) - one barrier
// per window, stage latency hidden under MFMA. Split-K path unchanged.
// ---------------------------------------------------------------------------

typedef _Float16 f16;
typedef _Float16 f16x8 __attribute__((ext_vector_type(8)));
typedef _Float16 f16x4 __attribute__((ext_vector_type(4)));
typedef float f32x4 __attribute__((ext_vector_type(4)));

__device__ __forceinline__ int xcd_swz(int bx, int nbx) {
  const int q = nbx >> 3, r = nbx & 7;
  const int x = bx & 7, o = bx >> 3;
  return (x < r ? x * (q + 1) : r * (q + 1) + (x - r) * q) + o;
}

// ---------------- fused weight prep (all 8 layers, one launch) --------------
struct WArgs {
  const float* src[8];
  int end[8];
  int S[8], G[8], CR[8], CO[8];
};
__global__ __launch_bounds__(256) void wprep_all(WArgs a, f16* __restrict__ wf)
{
  const int e = blockIdx.x * 256 + threadIdx.x;
  int li = 0;
  while (li < 7 && e >= a.end[li]) ++li;
  if (e >= a.end[li]) return;
  const int base = li ? a.end[li - 1] : 0;
  int x = e - base;
  const int i = x & 7;
  const int l = (x >> 3) & 63;
  int r = x >> 9;
  const int g = r % a.G[li]; r /= a.G[li];
  const int s = r % a.S[li]; r /= a.S[li];
  const int t = r;
  const int k = s * 32 + ((l >> 4) << 3) + i;
  const int co = g * 16 + (l & 15);
  float v;
  if (li == 0) {
    const int tap = k >> 3, ci = k & 7;
    v = (ci < 3 && tap < 27) ? a.src[0][((long)tap * 3 + ci) * 64 + co] : 0.f;
  } else {
    v = (k < a.CR[li]) ? a.src[li][((long)t * a.CR[li] + k) * a.CO[li] + co] : 0.f;
  }
  wf[e] = (f16)v;
}

// ---------------- conv1: 3ch->64, packed K (4 taps x 8ci), 7 K-steps -------
__global__ __launch_bounds__(256) void conv1_mfma(
    const float* __restrict__ xin, const f16* __restrict__ wf,
    f16* __restrict__ out, float* __restrict__ part)
{
  constexpr int Z = 64, Y = 64, X = 64, L = 4;
  constexpr int RB = 48;
  constexpr int SLAB = (L + 2) * (Z + 2) * RB;
  __shared__ __align__(16) char slab[3 * SLAB];
  __shared__ float sstat[4][2][64];

  const int tid = threadIdx.x;
  const int lane = tid & 63;
  const int wr = tid >> 6;

  const int bxs = xcd_swz(blockIdx.x, gridDim.x);
  const long vb = (long)bxs * 256;
  const int n = (int)(vb >> 18);
  const int rem = (int)(vb & 262143);
  const int x0 = rem >> 12;
  const int y0 = (rem >> 6) & 63;

  if (tid < 36) {
    const int s = tid / 12, pr = tid % 12;
    const int row = (pr >> 1) * (Z + 2) + (pr & 1) * (Z + 1);
    const f16x8 hz = {};
    *(f16x8*)(slab + s * SLAB + row * RB) = hz;
  }

  for (int rr2 = tid; rr2 < 3 * (L + 2) * Z; rr2 += 256) {
    const int s = rr2 / ((L + 2) * Z);
    const int rr = rr2 % ((L + 2) * Z);
    const int li = rr / Z, z = rr % Z;
    const int xs = x0 + s - 1, ys = y0 - 1 + li;
    f16x8 h = {};
    if (xs >= 0 && xs < X && ys >= 0 && ys < Y) {
      const float* p = xin + (((long)(n * X + xs) * Y + ys) * Z + z) * 3;
      h[0] = (f16)p[0]; h[1] = (f16)p[1]; h[2] = (f16)p[2];
    }
    *(f16x8*)(slab + s * SLAB + (li * (Z + 2) + 1 + z) * RB) = h;
  }

  int abase[4];
  #pragma unroll
  for (int r = 0; r < 4; ++r) {
    const int vl = wr * 64 + r * 16 + (lane & 15);
    abase[r] = ((vl >> 6) * (Z + 2) + (vl & 63)) * RB;
  }
  const int c = lane >> 4;
  int rofftab[7];
  #pragma unroll
  for (int j = 0; j < 7; ++j) {
    const int tap = 4 * j + c;
    if (tap < 27) {
      const int dx = tap / 9, dy = (tap / 3) % 3, dz = tap % 3;
      rofftab[j] = dx * SLAB + (dy * (Z + 2) + dz) * RB;
    } else {
      rofftab[j] = 0;
    }
  }

  f32x4 acc[4][4];
  const f32x4 fz = {0.f, 0.f, 0.f, 0.f};
  #pragma unroll
  for (int r = 0; r < 4; ++r)
    #pragma unroll
    for (int cc = 0; cc < 4; ++cc) acc[r][cc] = fz;

  __syncthreads();

  #pragma unroll
  for (int j = 0; j < 7; ++j) {
    f16x8 av[4];
    #pragma unroll
    for (int r = 0; r < 4; ++r)
      av[r] = *(const f16x8*)(slab + abase[r] + rofftab[j]);
    f16x8 bv[4];
    #pragma unroll
    for (int c2 = 0; c2 < 4; ++c2)
      bv[c2] = *(const f16x8*)((const char*)wf + ((j * 4 + c2) << 10) + (lane << 4));
    #pragma unroll
    for (int r = 0; r < 4; ++r)
      #pragma unroll
      for (int c2 = 0; c2 < 4; ++c2)
        acc[r][c2] = __builtin_amdgcn_mfma_f32_16x16x32_f16(av[r], bv[c2], acc[r][c2], 0, 0, 0);
  }

  const long vgbase = vb + wr * 64;
  #pragma unroll
  for (int r = 0; r < 4; ++r)
    #pragma unroll
    for (int cc = 0; cc < 4; ++cc)
      #pragma unroll
      for (int q = 0; q < 4; ++q) {
        const long vox = vgbase + r * 16 + ((lane >> 4) << 2) + q;
        const int co = cc * 16 + (lane & 15);
        out[vox * 64 + co] = (f16)acc[r][cc][q];
      }

  float s4[4], q4[4];
  #pragma unroll
  for (int cc = 0; cc < 4; ++cc) {
    float s = 0.f, q = 0.f;
    #pragma unroll
    for (int r = 0; r < 4; ++r)
      #pragma unroll
      for (int qd = 0; qd < 4; ++qd) {
        const float v = acc[r][cc][qd];
        s += v;
        q = fmaf(v, v, q);
      }
    s4[cc] = s; q4[cc] = q;
  }
  #pragma unroll
  for (int cc = 0; cc < 4; ++cc) {
    s4[cc] += __shfl_xor(s4[cc], 16);
    s4[cc] += __shfl_xor(s4[cc], 32);
    q4[cc] += __shfl_xor(q4[cc], 16);
    q4[cc] += __shfl_xor(q4[cc], 32);
  }
  if (lane < 16) {
    #pragma unroll
    for (int cc = 0; cc < 4; ++cc) {
      sstat[wr][0][cc * 16 + lane] = s4[cc];
      sstat[wr][1][cc * 16 + lane] = q4[cc];
    }
  }
  __syncthreads();
  for (int t = tid; t < 128; t += 256) {
    const int k = (t >> 6) & 1, ch = t & 63;
    float v = 0.f;
    #pragma unroll
    for (int w2 = 0; w2 < 4; ++w2) v += sstat[w2][k][ch];
    part[(long)bxs * 128 + k * 64 + ch] = v;
  }
}

// ---------------- ring-2 z-half pipelined conv (non-split layers) ----------
// Windows k=0..5: dx=k>>1, zh=k&1. Compute Hk from buf[k&1] while
// prefetching Hk+1 (global->regs before MFMAs, BN+ds_write after).
// Fragment r belongs to half zh_of(r) = ((r*16)%Z)/(Z/2).
template<int CIN, int Z, int WR, int WC, bool HASBN>
__global__ __launch_bounds__(WR*WC*64) void conv_pipe(
    const f16* __restrict__ xin, const f16* __restrict__ wf,
    f16* __restrict__ out, int X, int Y, int Co,
    const float* __restrict__ sc, const float* __restrict__ sh,
    float* __restrict__ part, int partBase)
{
  constexpr int NTHR = WR * WC * 64;
  constexpr int L = 64 * WR / Z;
  constexpr int ZH = Z / 2;
  constexpr int ZR = ZH + 2;                  // z-rows per line per half
  constexpr int RBB = CIN * 2;
  constexpr int HROWS = (L + 2) * ZR;
  constexpr int NE_H = HROWS * CIN;
  constexpr int NLD = (NE_H + NTHR * 8 - 1) / (NTHR * 8);
  constexpr int NL2 = (NLD + 1) / 2;
  constexpr int S = CIN / 32;
  constexpr int SH2 = S / 2;                  // s per half-window (S>=2)
  constexpr int COW = 64 * WC;
  __shared__ __align__(16) char slab[2][HROWS * RBB];
  __shared__ float sstat[WR * WC][2][64];

  const int tid = threadIdx.x;
  const int lane = tid & 63;
  const int wv = tid >> 6;
  const int wr = wv / WC, wc = wv % WC;

  const int bxs = xcd_swz(blockIdx.x, gridDim.x);
  const long vb = (long)bxs * (64 * WR);
  const int XYZ = X * Y * Z;
  const int n = (int)(vb / XYZ);
  const int rem = (int)(vb % XYZ);
  const int x0 = rem / (Y * Z);
  const int y0 = (rem % (Y * Z)) / Z;
  const int co0 = blockIdx.y * COW;
  const int Gtot = Co >> 4;
  const int g0 = (co0 >> 4) + wc * 4;

  // local row base per fragment (within its half-slab)
  int arow[4];
  #pragma unroll
  for (int r = 0; r < 4; ++r) {
    const int vl = wr * 64 + r * 16 + (lane & 15);
    arow[r] = (vl / Z) * ZR + ((r * 16) % ZH) + (lane & 15);
  }
  const int kbyte = (lane >> 4) << 4;

  f32x4 acc[4][4];
  const f32x4 fz = {0.f, 0.f, 0.f, 0.f};
  #pragma unroll
  for (int r = 0; r < 4; ++r)
    #pragma unroll
    for (int c = 0; c < 4; ++c) acc[r][c] = fz;

  f16x8 regs[NL2];

  // LOADH: issue global loads for half-tile k1, batch `half` -> regs
  auto LOADH = [&](int k1, int half) {
    const int dx = k1 >> 1, zh = k1 & 1;
    const int xs = x0 + dx - 1;
    const long gplane = (long)(n * X + xs) * Y;
    #pragma unroll
    for (int j = 0; j < NL2; ++j) {
      const int slot = half * NL2 + j;
      const int e = tid * 8 + slot * NTHR * 8;
      f16x8 h = {};
      if (slot < NLD && e < NE_H) {
        const int rr = e / CIN, ci = e % CIN;
        const int li = rr / ZR, zr = rr % ZR;
        const int ys = y0 - 1 + li;
        const int zs = zh * ZH - 1 + zr;
        if (xs >= 0 && xs < X && ys >= 0 && ys < Y && zs >= 0 && zs < Z)
          h = *(const f16x8*)(xin + ((gplane + ys) * Z + zs) * CIN + ci);
      }
      regs[j] = h;
    }
  };

  // WRITEH: BN (valid elems only) + swizzled ds_write into buf[k1&1]
  auto WRITEH = [&](int k1, int half) {
    const int dx = k1 >> 1, zh = k1 & 1;
    const int xs = x0 + dx - 1;
    char* buf = slab[k1 & 1];
    #pragma unroll
    for (int j = 0; j < NL2; ++j) {
      const int slot = half * NL2 + j;
      const int e = tid * 8 + slot * NTHR * 8;
      if (slot < NLD && e < NE_H) {
        const int rr = e / CIN, ci = e % CIN;
        const int li = rr / ZR, zr = rr % ZR;
        const int ys = y0 - 1 + li;
        const int zs = zh * ZH - 1 + zr;
        f16x8 h = regs[j];
        if constexpr (HASBN) {
          if (xs >= 0 && xs < X && ys >= 0 && ys < Y && zs >= 0 && zs < Z) {
            const float4 s0 = *(const float4*)(sc + ci);
            const float4 s1 = *(const float4*)(sc + ci + 4);
            const float4 h0 = *(const float4*)(sh + ci);
            const float4 h1 = *(const float4*)(sh + ci + 4);
            h[0] = (f16)fmaxf(fmaf((float)h[0], s0.x, h0.x), 0.f);
            h[1] = (f16)fmaxf(fmaf((float)h[1], s0.y, h0.y), 0.f);
            h[2] = (f16)fmaxf(fmaf((float)h[2], s0.z, h0.z), 0.f);
            h[3] = (f16)fmaxf(fmaf((float)h[3], s0.w, h0.w), 0.f);
            h[4] = (f16)fmaxf(fmaf((float)h[4], s1.x, h1.x), 0.f);
            h[5] = (f16)fmaxf(fmaf((float)h[5], s1.y, h1.y), 0.f);
            h[6] = (f16)fmaxf(fmaf((float)h[6], s1.z, h1.z), 0.f);
            h[7] = (f16)fmaxf(fmaf((float)h[7], s1.w, h1.w), 0.f);
          }
        }
        *(f16x8*)(buf + rr * RBB + ((ci * 2) ^ ((rr & 7) << 4))) = h;
      }
    }
  };

  // compute one s-step of window k (2 active fragments)
  auto ktaps = [&](int k, int s) {
    const int dx = k >> 1, zh = k & 1;
    const char* buf = slab[k & 1];
    #pragma unroll
    for (int dy = 0; dy < 3; ++dy) {
      #pragma unroll
      for (int dzi = 0; dzi < 3; ++dzi) {
        f16x8 av[4];
        #pragma unroll
        for (int r = 0; r < 4; ++r) {
          if (((r * 16) % Z) / ZH == zh) {
            const int row = arow[r] + dy * ZR + dzi;
            av[r] = *(const f16x8*)(buf + row * RBB +
                      ((s * 64 + kbyte) ^ ((row & 7) << 4)));
          }
        }
        const int t = dx * 9 + dy * 3 + dzi;
        f16x8 bv[4];
        #pragma unroll
        for (int c = 0; c < 4; ++c)
          bv[c] = *(const f16x8*)((const char*)wf +
                    (((long)(t * S + s) * Gtot + g0 + c) << 10) + (lane << 4));
        #pragma unroll
        for (int r = 0; r < 4; ++r) {
          if (((r * 16) % Z) / ZH == zh) {
            #pragma unroll
            for (int c = 0; c < 4; ++c)
              acc[r][c] = __builtin_amdgcn_mfma_f32_16x16x32_f16(av[r], bv[c], acc[r][c], 0, 0, 0);
          }
        }
      }
    }
  };

  // prologue: stage H0
  LOADH(0, 0); WRITEH(0, 0);
  LOADH(0, 1); WRITEH(0, 1);
  __syncthreads();

  for (int k = 0; k < 6; ++k) {
    if (k < 5) LOADH(k + 1, 0);
    for (int si = 0; si < SH2; ++si) ktaps(k, si);
    if (k < 5) WRITEH(k + 1, 0);
    if (k < 5) LOADH(k + 1, 1);
    for (int si = SH2; si < S; ++si) ktaps(k, si);
    if (k < 5) WRITEH(k + 1, 1);
    __syncthreads();
  }

  // epilogue: f16 out + fused stats
  const long vgbase = vb + wr * 64;
  const int cobase = co0 + wc * 64;
  #pragma unroll
  for (int r = 0; r < 4; ++r)
    #pragma unroll
    for (int c = 0; c < 4; ++c)
      #pragma unroll
      for (int q = 0; q < 4; ++q) {
        const long vox = vgbase + r * 16 + ((lane >> 4) << 2) + q;
        const int co = cobase + c * 16 + (lane & 15);
        out[vox * Co + co] = (f16)acc[r][c][q];
      }

  float s4[4], q4[4];
  #pragma unroll
  for (int c = 0; c < 4; ++c) {
    float s = 0.f, q = 0.f;
    #pragma unroll
    for (int r = 0; r < 4; ++r)
      #pragma unroll
      for (int qd = 0; qd < 4; ++qd) {
        const float v = acc[r][c][qd];
        s += v;
        q = fmaf(v, v, q);
      }
    s4[c] = s; q4[c] = q;
  }
  #pragma unroll
  for (int c = 0; c < 4; ++c) {
    s4[c] += __shfl_xor(s4[c], 16);
    s4[c] += __shfl_xor(s4[c], 32);
    q4[c] += __shfl_xor(q4[c], 16);
    q4[c] += __shfl_xor(q4[c], 32);
  }
  if (lane < 16) {
    #pragma unroll
    for (int c = 0; c < 4; ++c) {
      sstat[wv][0][c * 16 + lane] = s4[c];
      sstat[wv][1][c * 16 + lane] = q4[c];
    }
  }
  __syncthreads();
  const long entry = (long)blockIdx.y * gridDim.x + bxs + partBase;
  for (int t = tid; t < WC * 128; t += NTHR) {
    const int wcc = t >> 7, k = (t >> 6) & 1, ch = t & 63;
    float v = 0.f;
    #pragma unroll
    for (int wr2 = 0; wr2 < WR; ++wr2) v += sstat[wr2 * WC + wcc][k][ch];
    part[entry * (2 * COW) + k * COW + wcc * 64 + ch] = v;
  }
}

// ---------------- split-K conv (stage 3/4), unchanged from R9 ---------------
template<int CIN, int Z, int WR, int WC, bool HASBN, int SS>
__global__ __launch_bounds__(WR*WC*64) void conv_mfma(
    const f16* __restrict__ xin, const f16* __restrict__ wf,
    f16* __restrict__ out, int X, int Y, int Co,
    const float* __restrict__ sc, const float* __restrict__ sh,
    float* __restrict__ part, int partBase,
    float* __restrict__ pout, long outE)
{
  constexpr int NTHR = WR * WC * 64;
  constexpr int L = 64 * WR / Z;
  constexpr int RB = CIN * 2;
  constexpr int S = CIN / 32;
  __shared__ __align__(16) char slab[(L + 2) * (Z + 2) * RB];

  const int tid = threadIdx.x;
  const int lane = tid & 63;
  const int wv = tid >> 6;
  const int wr = wv / WC, wc = wv % WC;

  const int bxs = xcd_swz(blockIdx.x, gridDim.x);
  const long vb = (long)bxs * (64 * WR);
  const int XYZ = X * Y * Z;
  const int n = (int)(vb / XYZ);
  const int rem = (int)(vb % XYZ);
  const int x0 = rem / (Y * Z);
  const int y0 = (rem % (Y * Z)) / Z;
  const int co0 = blockIdx.y * (64 * WC);
  const int Gtot = Co >> 4;
  const int g0 = (co0 >> 4) + wc * 4;

  int arow[4];
  #pragma unroll
  for (int r = 0; r < 4; ++r) {
    const int vl = wr * 64 + r * 16 + (lane & 15);
    arow[r] = (vl / Z) * (Z + 2) + (vl % Z);
  }
  const int kbyte = (lane >> 4) << 4;

  f32x4 acc[4][4];
  const f32x4 fz = {0.f, 0.f, 0.f, 0.f};
  #pragma unroll
  for (int r = 0; r < 4; ++r)
    #pragma unroll
    for (int c = 0; c < 4; ++c) acc[r][c] = fz;

  {
    const f16x8 hz = {};
    for (int e = tid * 8; e < (L + 2) * 2 * CIN; e += NTHR * 8) {
      const int pr = e / CIN, ci = e % CIN;
      const int row = (pr >> 1) * (Z + 2) + (pr & 1) * (Z + 1);
      *(f16x8*)(slab + row * RB + ((ci * 2) ^ ((row & 7) << 4))) = hz;
    }
  }

  const int zb = blockIdx.z;
  const int dx = zb / SS;
  const int s0 = (zb % SS) * (S / SS);
  {
    const int xs = x0 + dx - 1;
    const bool xok = (xs >= 0) && (xs < X);
    const long gv0 = ((long)(n * X + xs) * Y + (y0 - 1)) * Z;
    constexpr int NE = (L + 2) * Z * CIN;
    for (int e = tid * 8; e < NE; e += NTHR * 8) {
      const int rr = e / CIN, ci = e % CIN;
      const int li = rr / Z, z = rr % Z;
      const int ys = y0 - 1 + li;
      f16x8 h = {};
      if (xok && ys >= 0 && ys < Y) {
        h = *(const f16x8*)(xin + (gv0 + rr) * CIN + ci);
        if constexpr (HASBN) {
          const float4 sc0 = *(const float4*)(sc + ci);
          const float4 sc1 = *(const float4*)(sc + ci + 4);
          const float4 sh0 = *(const float4*)(sh + ci);
          const float4 sh1 = *(const float4*)(sh + ci + 4);
          h[0] = (f16)fmaxf(fmaf((float)h[0], sc0.x, sh0.x), 0.f);
          h[1] = (f16)fmaxf(fmaf((float)h[1], sc0.y, sh0.y), 0.f);
          h[2] = (f16)fmaxf(fmaf((float)h[2], sc0.z, sh0.z), 0.f);
          h[3] = (f16)fmaxf(fmaf((float)h[3], sc0.w, sh0.w), 0.f);
          h[4] = (f16)fmaxf(fmaf((float)h[4], sc1.x, sh1.x), 0.f);
          h[5] = (f16)fmaxf(fmaf((float)h[5], sc1.y, sh1.y), 0.f);
          h[6] = (f16)fmaxf(fmaf((float)h[6], sc1.z, sh1.z), 0.f);
          h[7] = (f16)fmaxf(fmaf((float)h[7], sc1.w, sh1.w), 0.f);
        }
      }
      const int row = li * (Z + 2) + 1 + z;
      *(f16x8*)(slab + row * RB + ((ci * 2) ^ ((row & 7) << 4))) = h;
    }
  }
  __syncthreads();

  for (int si = 0; si < S / SS; ++si) {
    const int s = s0 + si;
    #pragma unroll
    for (int dy = 0; dy < 3; ++dy) {
      #pragma unroll
      for (int dzi = 0; dzi < 3; ++dzi) {
        f16x8 av[4];
        #pragma unroll
        for (int r = 0; r < 4; ++r) {
          const int row = arow[r] + dy * (Z + 2) + dzi;
          av[r] = *(const f16x8*)(slab + row * RB +
                    ((s * 64 + kbyte) ^ ((row & 7) << 4)));
        }
        const int t = dx * 9 + dy * 3 + dzi;
        f16x8 bv[4];
        #pragma unroll
        for (int c = 0; c < 4; ++c)
          bv[c] = *(const f16x8*)((const char*)wf +
                    (((long)(t * S + s) * Gtot + g0 + c) << 10) + (lane << 4));
        #pragma unroll
        for (int r = 0; r < 4; ++r)
          #pragma unroll
          for (int c = 0; c < 4; ++c)
            acc[r][c] = __builtin_amdgcn_mfma_f32_16x16x32_f16(av[r], bv[c], acc[r][c], 0, 0, 0);
      }
    }
  }

  const long vgbase = vb + wr * 64;
  const int cobase = co0 + wc * 64;
  float* pb = pout + (long)blockIdx.z * outE;
  #pragma unroll
  for (int r = 0; r < 4; ++r)
    #pragma unroll
    for (int c = 0; c < 4; ++c)
      #pragma unroll
      for (int q = 0; q < 4; ++q) {
        const long vox = vgbase + r * 16 + ((lane >> 4) << 2) + q;
        const int co = cobase + c * 16 + (lane & 15);
        pb[vox * Co + co] = acc[r][c][q];
      }
}

// ------- split-K reduce: sum KS f32 partials -> f16 out, stats partials ----
__global__ __launch_bounds__(256) void reduce_stats(
    const float* __restrict__ pout, f16* __restrict__ out,
    long outE, int KS, int vpb, float* __restrict__ part)
{
  const int tid = threadIdx.x;
  const int wv = tid >> 6, lane = tid & 63;
  const int vbase = blockIdx.x * vpb;
  float4 s = {0.f, 0.f, 0.f, 0.f}, q = {0.f, 0.f, 0.f, 0.f};
  for (int v = vbase + wv; v < vbase + vpb; v += 4) {
    const long e = (long)v * 256 + lane * 4;
    float4 o = *(const float4*)(pout + e);
    for (int z = 1; z < KS; ++z) {
      const float4 p = *(const float4*)(pout + (long)z * outE + e);
      o.x += p.x; o.y += p.y; o.z += p.z; o.w += p.w;
    }
    f16x4 ov = {(f16)o.x, (f16)o.y, (f16)o.z, (f16)o.w};
    *(f16x4*)(out + e) = ov;
    s.x += o.x; s.y += o.y; s.z += o.z; s.w += o.w;
    q.x = fmaf(o.x, o.x, q.x); q.y = fmaf(o.y, o.y, q.y);
    q.z = fmaf(o.z, o.z, q.z); q.w = fmaf(o.w, o.w, q.w);
  }
  __shared__ float st[4][2][256];
  *(float4*)&st[wv][0][lane * 4] = s;
  *(float4*)&st[wv][1][lane * 4] = q;
  __syncthreads();
  for (int t = tid; t < 512; t += 256) {
    const int k = t >> 8, ch = t & 255;
    part[(long)blockIdx.x * 512 + k * 256 + ch] =
        st[0][k][ch] + st[1][k][ch] + st[2][k][ch] + st[3][k][ch];
  }
}

// ------- finalize: per-channel scale/shift from block partials -------------
__global__ __launch_bounds__(256) void stats_final(
    const float* __restrict__ part, int nbx, int CoWin, long nvox,
    const float* __restrict__ g, const float* __restrict__ b,
    float* __restrict__ sc, float* __restrict__ sh)
{
  const int c = blockIdx.x;
  const int by = c / CoWin;
  const int cw = c % CoWin;
  const int tid = threadIdx.x;
  float s = 0.f, ss = 0.f;
  for (int i = tid; i < nbx; i += 256) {
    const long base = ((long)by * nbx + i) * 2 * CoWin;
    s += part[base + cw];
    ss += part[base + CoWin + cw];
  }
  __shared__ float r0[256];
  __shared__ float r1[256];
  r0[tid] = s; r1[tid] = ss;
  __syncthreads();
  #pragma unroll
  for (int o = 128; o > 0; o >>= 1) {
    if (tid < o) { r0[tid] += r0[tid + o]; r1[tid] += r1[tid + o]; }
    __syncthreads();
  }
  if (tid == 0) {
    const float inv = 1.f / (float)nvox;
    const float m = r0[0] * inv;
    const float var = r1[0] * inv - m * m;
    const float scale = rsqrtf(var + 1e-5f) * g[c];
    sc[c] = scale;
    sh[c] = b[c] - m * scale;
  }
}

// maxpool(relu(bn(x))) == relu(bn(maxpool(x))) since bn scale > 0 here.
__global__ __launch_bounds__(256) void maxpool2_aff(
    const f16* __restrict__ in, f16* __restrict__ out,
    int N, int X, int Y, int Z, int C,
    const float* __restrict__ sc, const float* __restrict__ sh)
{
  const int OX = X >> 1, OY = Y >> 1, OZ = Z >> 1;
  const int c4n = C >> 2;
  const long nout = (long)N * OX * OY * OZ * c4n;
  long idx = (long)blockIdx.x * 256 + threadIdx.x;
  if (idx >= nout) return;
  const int c4 = (int)(idx % c4n);
  long v = idx / c4n;
  const int oz = (int)(v % OZ); v /= OZ;
  const int oy = (int)(v % OY); v /= OY;
  const int ox = (int)(v % OX);
  const int n = (int)(v / OX);
  const long sx = (long)Y * Z * C, sy = (long)Z * C, sz = C;
  const long base = ((((long)n * X + 2 * ox) * Y + 2 * oy) * Z + 2 * oz) * (long)C + 4L * c4;
  f16x4 m = *(const f16x4*)(in + base);
  #pragma unroll
  for (int dd = 1; dd < 8; ++dd) {
    const int dxp = dd >> 2, dyp = (dd >> 1) & 1, dzp = dd & 1;
    const f16x4 t = *(const f16x4*)(in + base + dxp * sx + dyp * sy + dzp * sz);
    #pragma unroll
    for (int i = 0; i < 4; ++i) m[i] = (t[i] > m[i]) ? t[i] : m[i];
  }
  const int c = 4 * c4;
  const float4 s4 = *(const float4*)(sc + c);
  const float4 h4 = *(const float4*)(sh + c);
  f16x4 r;
  r[0] = (f16)fmaxf(fmaf((float)m[0], s4.x, h4.x), 0.f);
  r[1] = (f16)fmaxf(fmaf((float)m[1], s4.y, h4.y), 0.f);
  r[2] = (f16)fmaxf(fmaf((float)m[2], s4.z, h4.z), 0.f);
  r[3] = (f16)fmaxf(fmaf((float)m[3], s4.w, h4.w), 0.f);
  *(f16x4*)(out + idx * 4) = r;
}

// ---- head stage A: BN8-affine(mean over 512 vox) -> hbuf[2][256] ----------
__global__ __launch_bounds__(256) void head_mean(
    const f16* __restrict__ x8, const float* __restrict__ sc, const float* __restrict__ sh,
    float* __restrict__ hbuf)
{
  const int n = blockIdx.x, cg = blockIdx.y;
  const int tx = threadIdx.x & 63, ty = threadIdx.x >> 6;
  const int c = cg * 64 + tx;
  float s = 0.f;
  for (int v = ty; v < 512; v += 4) s += (float)x8[((long)n * 512 + v) * 256 + c];
  __shared__ float red[4][64];
  red[ty][tx] = s;
  __syncthreads();
  if (ty == 0) {
    s = red[0][tx] + red[1][tx] + red[2][tx] + red[3][tx];
    hbuf[n * 256 + c] = fmaf(s * (1.f / 512.f), sc[c], sh[c]);
  }
}

// ---- head stage B: out = hbuf @ wl + bl ------------------------------------
__global__ __launch_bounds__(256) void head_mv(
    const float* __restrict__ hbuf, const float* __restrict__ wl,
    const float* __restrict__ bl, float* __restrict__ out)
{
  const int n = blockIdx.x, og = blockIdx.y;
  const int tx = threadIdx.x & 63, ty = threadIdx.x >> 6;
  const int oc = og * 64 + tx;
  float a = 0.f;
  const int k0 = ty * 64;
  for (int k = k0; k < k0 + 64; ++k)
    a = fmaf(hbuf[n * 256 + k], wl[(long)k * 256 + oc], a);
  __shared__ float red[4][64];
  red[ty][tx] = a;
  __syncthreads();
  if (ty == 0)
    out[n * 256 + oc] = red[0][tx] + red[1][tx] + red[2][tx] + red[3][tx] + bl[oc];
}

// ---------------------------------------------------------------------------
extern "C" void kernel_launch(void* const* d_in, const int* in_sizes, int n_in,
                              void* d_out, int out_size, void* d_ws, size_t ws_size,
                              hipStream_t stream)
{
  const float* x = (const float*)d_in[0];
  const float* W[8];
  const float* G[8];
  const float* B[8];
  for (int i = 0; i < 8; ++i) {
    W[i] = (const float*)d_in[1 + 3 * i];
    G[i] = (const float*)d_in[2 + 3 * i];
    B[i] = (const float*)d_in[3 + 3 * i];
  }
  const float* wl = (const float*)d_in[25];
  const float* bl = (const float*)d_in[26];

  // workspace carve-up
  char* ws = (char*)d_ws;
  f16*   A    = (f16*)ws;                          // 33,554,432 f16 (64 MiB)
  f16*   Bb   = (f16*)(ws + (64L << 20));          // 33,554,432 f16 (64 MiB)
  float* pK   = (float*)(ws + (128L << 20));       // 6,291,456 f32 (24 MiB)
  float* part = (float*)(ws + (152L << 20));       // 262,144 f32 (1 MiB)
  float* scb  = part + 262144L;                    // 8*256
  float* shb  = scb + 2048L;                       // 8*256
  float* hbuf = shb + 2048L;                       // 512
  f16*   wfb  = (f16*)(hbuf + 512L);               // packed weights ~14 MiB

  const int wfS[8]  = {7, 2, 2, 4, 4, 8, 8, 8};
  const int wfG[8]  = {4, 4, 8, 8, 16, 16, 16, 16};
  const int wfT[8]  = {1, 27, 27, 27, 27, 27, 27, 27};
  const int wfCR[8] = {3, 64, 64, 128, 128, 256, 256, 256};
  const int wfCO[8] = {64, 64, 128, 128, 256, 256, 256, 256};
  long wfOff[9];
  wfOff[0] = 0;
  for (int i = 0; i < 8; ++i) wfOff[i + 1] = wfOff[i] + (long)wfT[i] * wfS[i] * wfG[i] * 512;
  if (ws_size < (size_t)((char*)(wfb + wfOff[8]) - ws)) return;  // fail loud
  auto WF = [&](int i) { return wfb + wfOff[i]; };
  auto SC = [&](int i) { return scb + i * 256; };
  auto SH = [&](int i) { return shb + i * 256; };

  // ---- weight prep: one launch ----
  {
    WArgs a;
    for (int i = 0; i < 8; ++i) {
      a.src[i] = W[i]; a.end[i] = (int)wfOff[i + 1];
      a.S[i] = wfS[i]; a.G[i] = wfG[i]; a.CR[i] = wfCR[i]; a.CO[i] = wfCO[i];
    }
    wprep_all<<<(unsigned)((wfOff[8] + 255) / 256), 256, 0, stream>>>(a, wfb);
  }

  auto fin = [&](int layer, int nbx, int CoWin, int C, long nvox) {
    stats_final<<<C, 256, 0, stream>>>(part, nbx, CoWin, nvox,
                                       G[layer], B[layer], SC(layer), SH(layer));
  };
  auto pool_aff = [&](const f16* in, f16* ob, int N, int Xd, int Yd, int Zd, int C, int layer) {
    const long nout = (long)N * (Xd / 2) * (Yd / 2) * (Zd / 2) * (C / 4);
    maxpool2_aff<<<(unsigned)((nout + 255) / 256), 256, 0, stream>>>(
        in, ob, N, Xd, Yd, Zd, C, SC(layer), SH(layer));
  };

  // ---- stage 1: 64^3 ----
  conv1_mfma<<<2048, 256, 0, stream>>>(x, WF(0), A, part);
  fin(0, 2048, 64, 64, 524288);
  conv_pipe<64, 64, 4, 1, true><<<dim3(2048, 1), 256, 0, stream>>>(
      A, WF(1), Bb, 64, 64, 64, SC(0), SH(0), part, 0);
  fin(1, 2048, 64, 64, 524288);
  pool_aff(Bb, A, 2, 64, 64, 64, 64, 1);          // P = A[0:4M]

  // ---- stage 2: 32^3 ----
  conv_pipe<64, 32, 2, 2, false><<<dim3(512, 1), 256, 0, stream>>>(
      A, WF(2), Bb, 32, 32, 128, nullptr, nullptr, part, 0);
  fin(2, 512, 128, 128, 65536);
  conv_pipe<128, 32, 2, 2, true><<<dim3(512, 1), 256, 0, stream>>>(
      Bb, WF(3), A, 32, 32, 128, SC(2), SH(2), part, 0);
  fin(3, 512, 128, 128, 65536);
  pool_aff(A, Bb, 2, 32, 32, 32, 128, 3);         // Q = Bb[0:1M]

  // ---- stage 3: 16^3, split-K (KS=3 over dx) ----
  const long E16 = 2097152;                        // 8192 vox * 256 ch
  conv_mfma<128, 16, 1, 4, false, 1><<<dim3(128, 1, 3), 256, 0, stream>>>(
      Bb, WF(4), nullptr, 16, 16, 256, nullptr, nullptr, nullptr, 0, pK, E16);
  reduce_stats<<<256, 256, 0, stream>>>(pK, A, E16, 3, 32, part);
  fin(4, 256, 256, 256, 8192);
  conv_mfma<256, 16, 1, 4, true, 1><<<dim3(128, 1, 3), 256, 0, stream>>>(
      A, WF(5), nullptr, 16, 16, 256, SC(4), SH(4), nullptr, 0, pK, E16);
  reduce_stats<<<256, 256, 0, stream>>>(pK, Bb, E16, 3, 32, part);
  fin(5, 256, 256, 256, 8192);
  conv_mfma<256, 16, 1, 4, true, 1><<<dim3(128, 1, 3), 256, 0, stream>>>(
      Bb, WF(6), nullptr, 16, 16, 256, SC(5), SH(5), nullptr, 0, pK, E16);
  reduce_stats<<<256, 256, 0, stream>>>(pK, A, E16, 3, 32, part);
  fin(6, 256, 256, 256, 8192);
  pool_aff(A, Bb, 2, 16, 16, 16, 256, 6);         // R = Bb[0:256K]

  // ---- stage 4: 8^3, split-K KS=12 ----
  const long E8 = 262144;
  conv_mfma<256, 8, 1, 4, false, 4><<<dim3(16, 1, 12), 256, 0, stream>>>(
      Bb, WF(7), nullptr, 8, 8, 256, nullptr, nullptr, nullptr, 0, pK, E8);
  reduce_stats<<<256, 256, 0, stream>>>(pK, A, E8, 12, 4, part);
  fin(7, 256, 256, 256, 1024);

  // ---- head ----
  head_mean<<<dim3(2, 4), 256, 0, stream>>>(A, SC(7), SH(7), hbuf);
  head_mv<<<dim3(2, 4), 256, 0, stream>>>(hbuf, wl, bl, (float*)d_out);
}

// Round 12
// 578.407 us; speedup vs baseline: 1.2603x; 1.2603x over previous
//
#include <hip/hip_runtime.h>
#include <stdint.h>

// ---------------------------------------------------------------------------
// VGG16-3D forward. R11: best-known config (R6 pad-RB direct staging for
// conv3/4/splitK, conv1 K-packed) + conv2 rebuilt m97-style:
//   bnpad: BN+ReLU conv1-out into zero-PADDED [2][66^3][64] tensor
//   conv2_dma: staging = pure global_load_lds(16B) DMA from the padded
//   tensor (one contiguous 50.7KB span per dx), pre-swizzled source so the
//   linear LDS + XOR'd ds_read is bank-conflict-free (rule #21).
// ---------------------------------------------------------------------------

typedef _Float16 f16;
typedef _Float16 f16x8 __attribute__((ext_vector_type(8)));
typedef _Float16 f16x4 __attribute__((ext_vector_type(4)));
typedef float f32x4 __attribute__((ext_vector_type(4)));

__device__ __forceinline__ int xcd_swz(int bx, int nbx) {
  const int q = nbx >> 3, r = nbx & 7;
  const int x = bx & 7, o = bx >> 3;
  return (x < r ? x * (q + 1) : r * (q + 1) + (x - r) * q) + o;
}

// ---------------- fused weight prep (all 8 layers, one launch) --------------
// layers 1..7: [t][s][g][lane][i]; k = s*32 + (lane>>4)*8 + i, co = g*16+(lane&15)
// layer 0 (packed): k in [0,224): tap = k>>3 (27 real), ci = k&7 (3 real)
struct WArgs {
  const float* src[8];
  int end[8];
  int S[8], G[8], CR[8], CO[8];
};
__global__ __launch_bounds__(256) void wprep_all(WArgs a, f16* __restrict__ wf)
{
  const int e = blockIdx.x * 256 + threadIdx.x;
  int li = 0;
  while (li < 7 && e >= a.end[li]) ++li;
  if (e >= a.end[li]) return;
  const int base = li ? a.end[li - 1] : 0;
  int x = e - base;
  const int i = x & 7;
  const int l = (x >> 3) & 63;
  int r = x >> 9;
  const int g = r % a.G[li]; r /= a.G[li];
  const int s = r % a.S[li]; r /= a.S[li];
  const int t = r;
  const int k = s * 32 + ((l >> 4) << 3) + i;
  const int co = g * 16 + (l & 15);
  float v;
  if (li == 0) {
    const int tap = k >> 3, ci = k & 7;
    v = (ci < 3 && tap < 27) ? a.src[0][((long)tap * 3 + ci) * 64 + co] : 0.f;
  } else {
    v = (k < a.CR[li]) ? a.src[li][((long)t * a.CR[li] + k) * a.CO[li] + co] : 0.f;
  }
  wf[e] = (f16)v;
}

// ---------------- conv1: 3ch->64, packed K (4 taps x 8ci), 7 K-steps -------
__global__ __launch_bounds__(256) void conv1_mfma(
    const float* __restrict__ xin, const f16* __restrict__ wf,
    f16* __restrict__ out, float* __restrict__ part)
{
  constexpr int Z = 64, Y = 64, X = 64, L = 4;
  constexpr int RB = 48;
  constexpr int SLAB = (L + 2) * (Z + 2) * RB;
  __shared__ __align__(16) char slab[3 * SLAB];
  __shared__ float sstat[4][2][64];

  const int tid = threadIdx.x;
  const int lane = tid & 63;
  const int wr = tid >> 6;

  const int bxs = xcd_swz(blockIdx.x, gridDim.x);
  const long vb = (long)bxs * 256;
  const int n = (int)(vb >> 18);
  const int rem = (int)(vb & 262143);
  const int x0 = rem >> 12;
  const int y0 = (rem >> 6) & 63;

  if (tid < 36) {
    const int s = tid / 12, pr = tid % 12;
    const int row = (pr >> 1) * (Z + 2) + (pr & 1) * (Z + 1);
    const f16x8 hz = {};
    *(f16x8*)(slab + s * SLAB + row * RB) = hz;
  }

  for (int rr2 = tid; rr2 < 3 * (L + 2) * Z; rr2 += 256) {
    const int s = rr2 / ((L + 2) * Z);
    const int rr = rr2 % ((L + 2) * Z);
    const int li = rr / Z, z = rr % Z;
    const int xs = x0 + s - 1, ys = y0 - 1 + li;
    f16x8 h = {};
    if (xs >= 0 && xs < X && ys >= 0 && ys < Y) {
      const float* p = xin + (((long)(n * X + xs) * Y + ys) * Z + z) * 3;
      h[0] = (f16)p[0]; h[1] = (f16)p[1]; h[2] = (f16)p[2];
    }
    *(f16x8*)(slab + s * SLAB + (li * (Z + 2) + 1 + z) * RB) = h;
  }

  int abase[4];
  #pragma unroll
  for (int r = 0; r < 4; ++r) {
    const int vl = wr * 64 + r * 16 + (lane & 15);
    abase[r] = ((vl >> 6) * (Z + 2) + (vl & 63)) * RB;
  }
  const int c = lane >> 4;
  int rofftab[7];
  #pragma unroll
  for (int j = 0; j < 7; ++j) {
    const int tap = 4 * j + c;
    if (tap < 27) {
      const int dx = tap / 9, dy = (tap / 3) % 3, dz = tap % 3;
      rofftab[j] = dx * SLAB + (dy * (Z + 2) + dz) * RB;
    } else {
      rofftab[j] = 0;
    }
  }

  f32x4 acc[4][4];
  const f32x4 fz = {0.f, 0.f, 0.f, 0.f};
  #pragma unroll
  for (int r = 0; r < 4; ++r)
    #pragma unroll
    for (int cc = 0; cc < 4; ++cc) acc[r][cc] = fz;

  __syncthreads();

  #pragma unroll
  for (int j = 0; j < 7; ++j) {
    f16x8 av[4];
    #pragma unroll
    for (int r = 0; r < 4; ++r)
      av[r] = *(const f16x8*)(slab + abase[r] + rofftab[j]);
    f16x8 bv[4];
    #pragma unroll
    for (int c2 = 0; c2 < 4; ++c2)
      bv[c2] = *(const f16x8*)((const char*)wf + ((j * 4 + c2) << 10) + (lane << 4));
    #pragma unroll
    for (int r = 0; r < 4; ++r)
      #pragma unroll
      for (int c2 = 0; c2 < 4; ++c2)
        acc[r][c2] = __builtin_amdgcn_mfma_f32_16x16x32_f16(av[r], bv[c2], acc[r][c2], 0, 0, 0);
  }

  const long vgbase = vb + wr * 64;
  #pragma unroll
  for (int r = 0; r < 4; ++r)
    #pragma unroll
    for (int cc = 0; cc < 4; ++cc)
      #pragma unroll
      for (int q = 0; q < 4; ++q) {
        const long vox = vgbase + r * 16 + ((lane >> 4) << 2) + q;
        const int co = cc * 16 + (lane & 15);
        out[vox * 64 + co] = (f16)acc[r][cc][q];
      }

  float s4[4], q4[4];
  #pragma unroll
  for (int cc = 0; cc < 4; ++cc) {
    float s = 0.f, q = 0.f;
    #pragma unroll
    for (int r = 0; r < 4; ++r)
      #pragma unroll
      for (int qd = 0; qd < 4; ++qd) {
        const float v = acc[r][cc][qd];
        s += v;
        q = fmaf(v, v, q);
      }
    s4[cc] = s; q4[cc] = q;
  }
  #pragma unroll
  for (int cc = 0; cc < 4; ++cc) {
    s4[cc] += __shfl_xor(s4[cc], 16);
    s4[cc] += __shfl_xor(s4[cc], 32);
    q4[cc] += __shfl_xor(q4[cc], 16);
    q4[cc] += __shfl_xor(q4[cc], 32);
  }
  if (lane < 16) {
    #pragma unroll
    for (int cc = 0; cc < 4; ++cc) {
      sstat[wr][0][cc * 16 + lane] = s4[cc];
      sstat[wr][1][cc * 16 + lane] = q4[cc];
    }
  }
  __syncthreads();
  for (int t = tid; t < 128; t += 256) {
    const int k = (t >> 6) & 1, ch = t & 63;
    float v = 0.f;
    #pragma unroll
    for (int w2 = 0; w2 < 4; ++w2) v += sstat[w2][k][ch];
    part[(long)bxs * 128 + k * 64 + ch] = v;
  }
}

// ---- bnpad: BN+ReLU conv1-out into zero-padded [2][66][66][66][64] --------
__global__ __launch_bounds__(256) void bnpad(
    const f16* __restrict__ in, f16* __restrict__ outp,
    const float* __restrict__ sc, const float* __restrict__ sh)
{
  const long NT = 2L * 66 * 66 * 66 * 8;
  long idx = (long)blockIdx.x * 256 + threadIdx.x;
  if (idx >= NT) return;
  const int c8 = (int)(idx & 7);
  long v = idx >> 3;
  const int zp = (int)(v % 66); v /= 66;
  const int yp = (int)(v % 66); v /= 66;
  const int xp = (int)(v % 66);
  const int n = (int)(v / 66);
  f16x8 h = {};
  if (xp >= 1 && xp <= 64 && yp >= 1 && yp <= 64 && zp >= 1 && zp <= 64) {
    const long src = ((((long)n * 64 + xp - 1) * 64 + yp - 1) * 64 + zp - 1) * 64 + c8 * 8;
    h = *(const f16x8*)(in + src);
    const int ci = c8 * 8;
    const float4 s0 = *(const float4*)(sc + ci);
    const float4 s1 = *(const float4*)(sc + ci + 4);
    const float4 h0 = *(const float4*)(sh + ci);
    const float4 h1 = *(const float4*)(sh + ci + 4);
    h[0] = (f16)fmaxf(fmaf((float)h[0], s0.x, h0.x), 0.f);
    h[1] = (f16)fmaxf(fmaf((float)h[1], s0.y, h0.y), 0.f);
    h[2] = (f16)fmaxf(fmaf((float)h[2], s0.z, h0.z), 0.f);
    h[3] = (f16)fmaxf(fmaf((float)h[3], s0.w, h0.w), 0.f);
    h[4] = (f16)fmaxf(fmaf((float)h[4], s1.x, h1.x), 0.f);
    h[5] = (f16)fmaxf(fmaf((float)h[5], s1.y, h1.y), 0.f);
    h[6] = (f16)fmaxf(fmaf((float)h[6], s1.z, h1.z), 0.f);
    h[7] = (f16)fmaxf(fmaf((float)h[7], s1.w, h1.w), 0.f);
  }
  *(f16x8*)(outp + idx * 8) = h;
}

// ---- conv2: DMA-staged implicit GEMM from padded input --------------------
// Slab per dx = ONE contiguous 50,688B global span ([y][z][c] contiguous at
// fixed x). 50 x 1024B global_load_lds; source pre-swizzled (chunk j of row r
// holds global chunk j^(r&7)); ds_read applies the same XOR -> conflict-free.
__global__ __launch_bounds__(256) void conv2_dma(
    const f16* __restrict__ xp, const f16* __restrict__ wf,
    f16* __restrict__ out, float* __restrict__ part)
{
  constexpr int ZP = 66;
  constexpr int RB = 128;                 // 64 f16 per row
  constexpr int SLABB = 51200;            // 50 windows x 1024 (>= 396*128)
  __shared__ __align__(1024) char slab[SLABB];
  __shared__ float sstat[4][2][64];

  const int tid = threadIdx.x;
  const int lane = tid & 63;
  const int wv = tid >> 6;

  const int bxs = xcd_swz(blockIdx.x, gridDim.x);
  const long vb = (long)bxs * 256;
  const int n = (int)(vb >> 18);
  const int rem = (int)(vb & 262143);
  const int x0 = rem >> 12;               // [0,63]
  const int y0 = (rem >> 6) & 63;         // multiple of 4

  // per-lane pre-swizzled source offset within each 1024B window
  const int srcoff = ((lane >> 3) << 7) | ((((lane & 7) ^ ((lane >> 3) & 7))) << 4);

  int arow[4];
  #pragma unroll
  for (int r = 0; r < 4; ++r) {
    const int vl = wv * 64 + r * 16 + (lane & 15);
    arow[r] = (vl >> 6) * ZP + (vl & 63);
  }
  const int kbyte = (lane >> 4) << 4;

  f32x4 acc[4][4];
  const f32x4 fz = {0.f, 0.f, 0.f, 0.f};
  #pragma unroll
  for (int r = 0; r < 4; ++r)
    #pragma unroll
    for (int c = 0; c < 4; ++c) acc[r][c] = fz;

  for (int dx = 0; dx < 3; ++dx) {
    __syncthreads();   // slab free (previous dx's reads done)
    const char* gsrc = (const char*)xp +
        (((long)(n * 66 + (x0 + dx)) * 66 + y0) * (long)(ZP * 64 * 2));
    for (int i = wv; i < 50; i += 4) {
      __builtin_amdgcn_global_load_lds(
          (const __attribute__((address_space(1))) uint32_t*)(const void*)(gsrc + (long)i * 1024 + srcoff),
          (__attribute__((address_space(3))) uint32_t*)(void*)(slab + i * 1024),
          16, 0, 0);
    }
    __syncthreads();   // vmcnt drain + barrier: slab ready

    for (int s = 0; s < 2; ++s) {
      #pragma unroll
      for (int dy = 0; dy < 3; ++dy) {
        #pragma unroll
        for (int dzi = 0; dzi < 3; ++dzi) {
          f16x8 av[4];
          #pragma unroll
          for (int r = 0; r < 4; ++r) {
            const int row = arow[r] + dy * ZP + dzi;
            av[r] = *(const f16x8*)(slab + row * RB +
                      ((s * 64 + kbyte) ^ ((row & 7) << 4)));
          }
          const int t = dx * 9 + dy * 3 + dzi;
          f16x8 bv[4];
          #pragma unroll
          for (int c = 0; c < 4; ++c)
            bv[c] = *(const f16x8*)((const char*)wf +
                      (((long)(t * 2 + s) * 4 + c) << 10) + (lane << 4));
          #pragma unroll
          for (int r = 0; r < 4; ++r)
            #pragma unroll
            for (int c = 0; c < 4; ++c)
              acc[r][c] = __builtin_amdgcn_mfma_f32_16x16x32_f16(av[r], bv[c], acc[r][c], 0, 0, 0);
        }
      }
    }
  }

  // epilogue: f16 out + fused stats
  const long vgbase = vb + wv * 64;
  #pragma unroll
  for (int r = 0; r < 4; ++r)
    #pragma unroll
    for (int c = 0; c < 4; ++c)
      #pragma unroll
      for (int q = 0; q < 4; ++q) {
        const long vox = vgbase + r * 16 + ((lane >> 4) << 2) + q;
        const int co = c * 16 + (lane & 15);
        out[vox * 64 + co] = (f16)acc[r][c][q];
      }

  float s4[4], q4[4];
  #pragma unroll
  for (int c = 0; c < 4; ++c) {
    float s = 0.f, q = 0.f;
    #pragma unroll
    for (int r = 0; r < 4; ++r)
      #pragma unroll
      for (int qd = 0; qd < 4; ++qd) {
        const float v = acc[r][c][qd];
        s += v;
        q = fmaf(v, v, q);
      }
    s4[c] = s; q4[c] = q;
  }
  #pragma unroll
  for (int c = 0; c < 4; ++c) {
    s4[c] += __shfl_xor(s4[c], 16);
    s4[c] += __shfl_xor(s4[c], 32);
    q4[c] += __shfl_xor(q4[c], 16);
    q4[c] += __shfl_xor(q4[c], 32);
  }
  if (lane < 16) {
    #pragma unroll
    for (int c = 0; c < 4; ++c) {
      sstat[wv][0][c * 16 + lane] = s4[c];
      sstat[wv][1][c * 16 + lane] = q4[c];
    }
  }
  __syncthreads();
  for (int t = tid; t < 128; t += 256) {
    const int k = (t >> 6) & 1, ch = t & 63;
    float v = 0.f;
    #pragma unroll
    for (int w2 = 0; w2 < 4; ++w2) v += sstat[w2][k][ch];
    part[(long)bxs * 128 + k * 64 + ch] = v;
  }
}

// ---------------- implicit-GEMM conv3d (R6 config: pad-RB, direct stage) ---
template<int CIN, int Z, int WR, int WC, bool HASBN, int SS>
__global__ __launch_bounds__(WR*WC*64) void conv_mfma(
    const f16* __restrict__ xin, const f16* __restrict__ wf,
    f16* __restrict__ out, int X, int Y, int Co,
    const float* __restrict__ sc, const float* __restrict__ sh,
    float* __restrict__ part, int partBase,
    float* __restrict__ pout, long outE)
{
  constexpr int NTHR = WR * WC * 64;
  constexpr int L = 64 * WR / Z;
  constexpr int RB = (CIN + 8) * 2;       // +8 f16 pad (R6 config)
  constexpr int S = CIN / 32;
  constexpr int COW = 64 * WC;
  constexpr bool SPLIT = (SS > 0);
  __shared__ __align__(16) char slab[(L + 2) * (Z + 2) * RB];
  __shared__ float sstat[SPLIT ? 1 : WR * WC][2][64];

  const int tid = threadIdx.x;
  const int lane = tid & 63;
  const int wv = tid >> 6;
  const int wr = wv / WC, wc = wv % WC;

  const int bxs = xcd_swz(blockIdx.x, gridDim.x);
  const long vb = (long)bxs * (64 * WR);
  const int XYZ = X * Y * Z;
  const int n = (int)(vb / XYZ);
  const int rem = (int)(vb % XYZ);
  const int x0 = rem / (Y * Z);
  const int y0 = (rem % (Y * Z)) / Z;
  const int co0 = blockIdx.y * COW;
  const int Gtot = Co >> 4;
  const int g0 = (co0 >> 4) + wc * 4;

  int abase[4];
  #pragma unroll
  for (int r = 0; r < 4; ++r) {
    const int vl = wr * 64 + r * 16 + (lane & 15);
    abase[r] = ((vl / Z) * (Z + 2) + (vl % Z)) * RB + ((lane >> 4) << 4);
  }

  f32x4 acc[4][4];
  const f32x4 fz = {0.f, 0.f, 0.f, 0.f};
  #pragma unroll
  for (int r = 0; r < 4; ++r)
    #pragma unroll
    for (int c = 0; c < 4; ++c) acc[r][c] = fz;

  {
    const f16x8 hz = {};
    for (int e = tid * 8; e < (L + 2) * 2 * CIN; e += NTHR * 8) {
      const int pr = e / CIN, ci = e % CIN;
      const int row = (pr >> 1) * (Z + 2) + (pr & 1) * (Z + 1);
      *(f16x8*)(slab + row * RB + ci * 2) = hz;
    }
  }

  auto stage = [&](int dx) {
    const int xs = x0 + dx - 1;
    const bool xok = (xs >= 0) && (xs < X);
    const long gv0 = ((long)(n * X + xs) * Y + (y0 - 1)) * Z;
    constexpr int NE = (L + 2) * Z * CIN;
    for (int e = tid * 8; e < NE; e += NTHR * 8) {
      const int rr = e / CIN, ci = e % CIN;
      const int li = rr / Z, z = rr % Z;
      const int ys = y0 - 1 + li;
      f16x8 h = {};
      if (xok && ys >= 0 && ys < Y) {
        h = *(const f16x8*)(xin + (gv0 + rr) * CIN + ci);
        if constexpr (HASBN) {
          const float4 s0 = *(const float4*)(sc + ci);
          const float4 s1 = *(const float4*)(sc + ci + 4);
          const float4 h0 = *(const float4*)(sh + ci);
          const float4 h1 = *(const float4*)(sh + ci + 4);
          h[0] = (f16)fmaxf(fmaf((float)h[0], s0.x, h0.x), 0.f);
          h[1] = (f16)fmaxf(fmaf((float)h[1], s0.y, h0.y), 0.f);
          h[2] = (f16)fmaxf(fmaf((float)h[2], s0.z, h0.z), 0.f);
          h[3] = (f16)fmaxf(fmaf((float)h[3], s0.w, h0.w), 0.f);
          h[4] = (f16)fmaxf(fmaf((float)h[4], s1.x, h1.x), 0.f);
          h[5] = (f16)fmaxf(fmaf((float)h[5], s1.y, h1.y), 0.f);
          h[6] = (f16)fmaxf(fmaf((float)h[6], s1.z, h1.z), 0.f);
          h[7] = (f16)fmaxf(fmaf((float)h[7], s1.w, h1.w), 0.f);
        }
      }
      *(f16x8*)(slab + (li * (Z + 2) + 1 + z) * RB + ci * 2) = h;
    }
  };

  auto ktaps = [&](int dx, int s) {
    #pragma unroll
    for (int dy = 0; dy < 3; ++dy) {
      #pragma unroll
      for (int dzi = 0; dzi < 3; ++dzi) {
        f16x8 av[4];
        #pragma unroll
        for (int r = 0; r < 4; ++r)
          av[r] = *(const f16x8*)(slab + abase[r] + s * 64 + (dy * (Z + 2) + dzi) * RB);
        const int t = dx * 9 + dy * 3 + dzi;
        f16x8 bv[4];
        #pragma unroll
        for (int c = 0; c < 4; ++c)
          bv[c] = *(const f16x8*)((const char*)wf +
                    (((long)(t * S + s) * Gtot + g0 + c) << 10) + (lane << 4));
        #pragma unroll
        for (int r = 0; r < 4; ++r)
          #pragma unroll
          for (int c = 0; c < 4; ++c)
            acc[r][c] = __builtin_amdgcn_mfma_f32_16x16x32_f16(av[r], bv[c], acc[r][c], 0, 0, 0);
      }
    }
  };

  if constexpr (SPLIT) {
    constexpr int SCH = S / SS;
    const int zb = blockIdx.z;
    const int dx = zb / SS;
    const int s0 = (zb % SS) * SCH;
    stage(dx);
    __syncthreads();
    #pragma unroll
    for (int si = 0; si < SCH; ++si) ktaps(dx, s0 + si);
  } else {
    for (int dx = 0; dx < 3; ++dx) {
      __syncthreads();
      stage(dx);
      __syncthreads();
      for (int s = 0; s < S; ++s) ktaps(dx, s);
    }
  }

  const long vgbase = vb + wr * 64;
  const int cobase = co0 + wc * 64;
  if constexpr (SPLIT) {
    float* pb = pout + (long)blockIdx.z * outE;
    #pragma unroll
    for (int r = 0; r < 4; ++r)
      #pragma unroll
      for (int c = 0; c < 4; ++c)
        #pragma unroll
        for (int q = 0; q < 4; ++q) {
          const long vox = vgbase + r * 16 + ((lane >> 4) << 2) + q;
          const int co = cobase + c * 16 + (lane & 15);
          pb[vox * Co + co] = acc[r][c][q];
        }
    return;
  }

  #pragma unroll
  for (int r = 0; r < 4; ++r)
    #pragma unroll
    for (int c = 0; c < 4; ++c)
      #pragma unroll
      for (int q = 0; q < 4; ++q) {
        const long vox = vgbase + r * 16 + ((lane >> 4) << 2) + q;
        const int co = cobase + c * 16 + (lane & 15);
        out[vox * Co + co] = (f16)acc[r][c][q];
      }

  float s4[4], q4[4];
  #pragma unroll
  for (int c = 0; c < 4; ++c) {
    float s = 0.f, q = 0.f;
    #pragma unroll
    for (int r = 0; r < 4; ++r)
      #pragma unroll
      for (int qd = 0; qd < 4; ++qd) {
        const float v = acc[r][c][qd];
        s += v;
        q = fmaf(v, v, q);
      }
    s4[c] = s; q4[c] = q;
  }
  #pragma unroll
  for (int c = 0; c < 4; ++c) {
    s4[c] += __shfl_xor(s4[c], 16);
    s4[c] += __shfl_xor(s4[c], 32);
    q4[c] += __shfl_xor(q4[c], 16);
    q4[c] += __shfl_xor(q4[c], 32);
  }
  if (lane < 16) {
    #pragma unroll
    for (int c = 0; c < 4; ++c) {
      sstat[wv][0][c * 16 + lane] = s4[c];
      sstat[wv][1][c * 16 + lane] = q4[c];
    }
  }
  __syncthreads();
  const long entry = (long)blockIdx.y * gridDim.x + bxs + partBase;
  for (int t = tid; t < WC * 128; t += NTHR) {
    const int wcc = t >> 7, k = (t >> 6) & 1, ch = t & 63;
    float v = 0.f;
    #pragma unroll
    for (int wr2 = 0; wr2 < WR; ++wr2) v += sstat[wr2 * WC + wcc][k][ch];
    part[entry * (2 * COW) + k * COW + wcc * 64 + ch] = v;
  }
}

// ------- split-K reduce: sum KS f32 partials -> f16 out, stats partials ----
__global__ __launch_bounds__(256) void reduce_stats(
    const float* __restrict__ pout, f16* __restrict__ out,
    long outE, int KS, int vpb, float* __restrict__ part)
{
  const int tid = threadIdx.x;
  const int wv = tid >> 6, lane = tid & 63;
  const int vbase = blockIdx.x * vpb;
  float4 s = {0.f, 0.f, 0.f, 0.f}, q = {0.f, 0.f, 0.f, 0.f};
  for (int v = vbase + wv; v < vbase + vpb; v += 4) {
    const long e = (long)v * 256 + lane * 4;
    float4 o = *(const float4*)(pout + e);
    for (int z = 1; z < KS; ++z) {
      const float4 p = *(const float4*)(pout + (long)z * outE + e);
      o.x += p.x; o.y += p.y; o.z += p.z; o.w += p.w;
    }
    f16x4 ov = {(f16)o.x, (f16)o.y, (f16)o.z, (f16)o.w};
    *(f16x4*)(out + e) = ov;
    s.x += o.x; s.y += o.y; s.z += o.z; s.w += o.w;
    q.x = fmaf(o.x, o.x, q.x); q.y = fmaf(o.y, o.y, q.y);
    q.z = fmaf(o.z, o.z, q.z); q.w = fmaf(o.w, o.w, q.w);
  }
  __shared__ float st[4][2][256];
  *(float4*)&st[wv][0][lane * 4] = s;
  *(float4*)&st[wv][1][lane * 4] = q;
  __syncthreads();
  for (int t = tid; t < 512; t += 256) {
    const int k = t >> 8, ch = t & 255;
    part[(long)blockIdx.x * 512 + k * 256 + ch] =
        st[0][k][ch] + st[1][k][ch] + st[2][k][ch] + st[3][k][ch];
  }
}

// ------- finalize: per-channel scale/shift from block partials -------------
__global__ __launch_bounds__(256) void stats_final(
    const float* __restrict__ part, int nbx, int CoWin, long nvox,
    const float* __restrict__ g, const float* __restrict__ b,
    float* __restrict__ sc, float* __restrict__ sh)
{
  const int c = blockIdx.x;
  const int by = c / CoWin;
  const int cw = c % CoWin;
  const int tid = threadIdx.x;
  float s = 0.f, ss = 0.f;
  for (int i = tid; i < nbx; i += 256) {
    const long base = ((long)by * nbx + i) * 2 * CoWin;
    s += part[base + cw];
    ss += part[base + CoWin + cw];
  }
  __shared__ float r0[256];
  __shared__ float r1[256];
  r0[tid] = s; r1[tid] = ss;
  __syncthreads();
  #pragma unroll
  for (int o = 128; o > 0; o >>= 1) {
    if (tid < o) { r0[tid] += r0[tid + o]; r1[tid] += r1[tid + o]; }
    __syncthreads();
  }
  if (tid == 0) {
    const float inv = 1.f / (float)nvox;
    const float m = r0[0] * inv;
    const float var = r1[0] * inv - m * m;
    const float scale = rsqrtf(var + 1e-5f) * g[c];
    sc[c] = scale;
    sh[c] = b[c] - m * scale;
  }
}

// maxpool(relu(bn(x))) == relu(bn(maxpool(x))) since bn scale > 0 here.
__global__ __launch_bounds__(256) void maxpool2_aff(
    const f16* __restrict__ in, f16* __restrict__ out,
    int N, int X, int Y, int Z, int C,
    const float* __restrict__ sc, const float* __restrict__ sh)
{
  const int OX = X >> 1, OY = Y >> 1, OZ = Z >> 1;
  const int c4n = C >> 2;
  const long nout = (long)N * OX * OY * OZ * c4n;
  long idx = (long)blockIdx.x * 256 + threadIdx.x;
  if (idx >= nout) return;
  const int c4 = (int)(idx % c4n);
  long v = idx / c4n;
  const int oz = (int)(v % OZ); v /= OZ;
  const int oy = (int)(v % OY); v /= OY;
  const int ox = (int)(v % OX);
  const int n = (int)(v / OX);
  const long sx = (long)Y * Z * C, sy = (long)Z * C, sz = C;
  const long base = ((((long)n * X + 2 * ox) * Y + 2 * oy) * Z + 2 * oz) * (long)C + 4L * c4;
  f16x4 m = *(const f16x4*)(in + base);
  #pragma unroll
  for (int dd = 1; dd < 8; ++dd) {
    const int dxp = dd >> 2, dyp = (dd >> 1) & 1, dzp = dd & 1;
    const f16x4 t = *(const f16x4*)(in + base + dxp * sx + dyp * sy + dzp * sz);
    #pragma unroll
    for (int i = 0; i < 4; ++i) m[i] = (t[i] > m[i]) ? t[i] : m[i];
  }
  const int c = 4 * c4;
  const float4 s4 = *(const float4*)(sc + c);
  const float4 h4 = *(const float4*)(sh + c);
  f16x4 r;
  r[0] = (f16)fmaxf(fmaf((float)m[0], s4.x, h4.x), 0.f);
  r[1] = (f16)fmaxf(fmaf((float)m[1], s4.y, h4.y), 0.f);
  r[2] = (f16)fmaxf(fmaf((float)m[2], s4.z, h4.z), 0.f);
  r[3] = (f16)fmaxf(fmaf((float)m[3], s4.w, h4.w), 0.f);
  *(f16x4*)(out + idx * 4) = r;
}

// ---- head stage A: BN8-affine(mean over 512 vox) -> hbuf[2][256] ----------
__global__ __launch_bounds__(256) void head_mean(
    const f16* __restrict__ x8, const float* __restrict__ sc, const float* __restrict__ sh,
    float* __restrict__ hbuf)
{
  const int n = blockIdx.x, cg = blockIdx.y;
  const int tx = threadIdx.x & 63, ty = threadIdx.x >> 6;
  const int c = cg * 64 + tx;
  float s = 0.f;
  for (int v = ty; v < 512; v += 4) s += (float)x8[((long)n * 512 + v) * 256 + c];
  __shared__ float red[4][64];
  red[ty][tx] = s;
  __syncthreads();
  if (ty == 0) {
    s = red[0][tx] + red[1][tx] + red[2][tx] + red[3][tx];
    hbuf[n * 256 + c] = fmaf(s * (1.f / 512.f), sc[c], sh[c]);
  }
}

// ---- head stage B: out = hbuf @ wl + bl ------------------------------------
__global__ __launch_bounds__(256) void head_mv(
    const float* __restrict__ hbuf, const float* __restrict__ wl,
    const float* __restrict__ bl, float* __restrict__ out)
{
  const int n = blockIdx.x, og = blockIdx.y;
  const int tx = threadIdx.x & 63, ty = threadIdx.x >> 6;
  const int oc = og * 64 + tx;
  float a = 0.f;
  const int k0 = ty * 64;
  for (int k = k0; k < k0 + 64; ++k)
    a = fmaf(hbuf[n * 256 + k], wl[(long)k * 256 + oc], a);
  __shared__ float red[4][64];
  red[ty][tx] = a;
  __syncthreads();
  if (ty == 0)
    out[n * 256 + oc] = red[0][tx] + red[1][tx] + red[2][tx] + red[3][tx] + bl[oc];
}

// ---------------------------------------------------------------------------
extern "C" void kernel_launch(void* const* d_in, const int* in_sizes, int n_in,
                              void* d_out, int out_size, void* d_ws, size_t ws_size,
                              hipStream_t stream)
{
  const float* x = (const float*)d_in[0];
  const float* W[8];
  const float* G[8];
  const float* B[8];
  for (int i = 0; i < 8; ++i) {
    W[i] = (const float*)d_in[1 + 3 * i];
    G[i] = (const float*)d_in[2 + 3 * i];
    B[i] = (const float*)d_in[3 + 3 * i];
  }
  const float* wl = (const float*)d_in[25];
  const float* bl = (const float*)d_in[26];

  // workspace carve-up
  char* ws = (char*)d_ws;
  f16*   A    = (f16*)ws;                          // 64 MiB (raw f16 tensors)
  f16*   Bb   = (f16*)(ws + (64L << 20));          // 64 MiB
  f16*   P1   = (f16*)(ws + (128L << 20));         // padded conv2 input 74.3 MiB
  float* pK   = (float*)(ws + (128L << 20));       // split-K partials (shares P1)
  float* part = (float*)(ws + (204L << 20));       // 1 MiB
  float* scb  = part + 262144L;
  float* shb  = scb + 2048L;
  float* hbuf = shb + 2048L;
  f16*   wfb  = (f16*)(hbuf + 512L);               // packed weights ~14 MiB

  const int wfS[8]  = {7, 2, 2, 4, 4, 8, 8, 8};
  const int wfG[8]  = {4, 4, 8, 8, 16, 16, 16, 16};
  const int wfT[8]  = {1, 27, 27, 27, 27, 27, 27, 27};
  const int wfCR[8] = {3, 64, 64, 128, 128, 256, 256, 256};
  const int wfCO[8] = {64, 64, 128, 128, 256, 256, 256, 256};
  long wfOff[9];
  wfOff[0] = 0;
  for (int i = 0; i < 8; ++i) wfOff[i + 1] = wfOff[i] + (long)wfT[i] * wfS[i] * wfG[i] * 512;
  if (ws_size < (size_t)((char*)(wfb + wfOff[8]) - ws)) return;  // fail loud
  auto WF = [&](int i) { return wfb + wfOff[i]; };
  auto SC = [&](int i) { return scb + i * 256; };
  auto SH = [&](int i) { return shb + i * 256; };

  // ---- weight prep: one launch ----
  {
    WArgs a;
    for (int i = 0; i < 8; ++i) {
      a.src[i] = W[i]; a.end[i] = (int)wfOff[i + 1];
      a.S[i] = wfS[i]; a.G[i] = wfG[i]; a.CR[i] = wfCR[i]; a.CO[i] = wfCO[i];
    }
    wprep_all<<<(unsigned)((wfOff[8] + 255) / 256), 256, 0, stream>>>(a, wfb);
  }

  auto fin = [&](int layer, int nbx, int CoWin, int C, long nvox) {
    stats_final<<<C, 256, 0, stream>>>(part, nbx, CoWin, nvox,
                                       G[layer], B[layer], SC(layer), SH(layer));
  };
  auto pool_aff = [&](const f16* in, f16* ob, int N, int Xd, int Yd, int Zd, int C, int layer) {
    const long nout = (long)N * (Xd / 2) * (Yd / 2) * (Zd / 2) * (C / 4);
    maxpool2_aff<<<(unsigned)((nout + 255) / 256), 256, 0, stream>>>(
        in, ob, N, Xd, Yd, Zd, C, SC(layer), SH(layer));
  };

  // ---- stage 1: 64^3 ----
  conv1_mfma<<<2048, 256, 0, stream>>>(x, WF(0), A, part);
  fin(0, 2048, 64, 64, 524288);
  {
    const long NT = 2L * 66 * 66 * 66 * 8;
    bnpad<<<(unsigned)((NT + 255) / 256), 256, 0, stream>>>(A, P1, SC(0), SH(0));
  }
  conv2_dma<<<2048, 256, 0, stream>>>(P1, WF(1), Bb, part);
  fin(1, 2048, 64, 64, 524288);
  pool_aff(Bb, A, 2, 64, 64, 64, 64, 1);          // P = A[0:4M]

  // ---- stage 2: 32^3 ----
  conv_mfma<64, 32, 2, 2, false, 0><<<dim3(512, 1), 256, 0, stream>>>(
      A, WF(2), Bb, 32, 32, 128, nullptr, nullptr, part, 0, nullptr, 0);
  fin(2, 512, 128, 128, 65536);
  conv_mfma<128, 32, 2, 2, true, 0><<<dim3(512, 1), 256, 0, stream>>>(
      Bb, WF(3), A, 32, 32, 128, SC(2), SH(2), part, 0, nullptr, 0);
  fin(3, 512, 128, 128, 65536);
  pool_aff(A, Bb, 2, 32, 32, 32, 128, 3);         // Q = Bb[0:1M]

  // ---- stage 3: 16^3, split-K (KS=3 over dx) ----
  const long E16 = 2097152;                        // 8192 vox * 256 ch
  conv_mfma<128, 16, 1, 4, false, 1><<<dim3(128, 1, 3), 256, 0, stream>>>(
      Bb, WF(4), nullptr, 16, 16, 256, nullptr, nullptr, nullptr, 0, pK, E16);
  reduce_stats<<<256, 256, 0, stream>>>(pK, A, E16, 3, 32, part);
  fin(4, 256, 256, 256, 8192);
  conv_mfma<256, 16, 1, 4, true, 1><<<dim3(128, 1, 3), 256, 0, stream>>>(
      A, WF(5), nullptr, 16, 16, 256, SC(4), SH(4), nullptr, 0, pK, E16);
  reduce_stats<<<256, 256, 0, stream>>>(pK, Bb, E16, 3, 32, part);
  fin(5, 256, 256, 256, 8192);
  conv_mfma<256, 16, 1, 4, true, 1><<<dim3(128, 1, 3), 256, 0, stream>>>(
      Bb, WF(6), nullptr, 16, 16, 256, SC(5), SH(5), nullptr, 0, pK, E16);
  reduce_stats<<<256, 256, 0, stream>>>(pK, A, E16, 3, 32, part);
  fin(6, 256, 256, 256, 8192);
  pool_aff(A, Bb, 2, 16, 16, 16, 256, 6);         // R = Bb[0:256K]

  // ---- stage 4: 8^3, split-K KS=12 ----
  const long E8 = 262144;
  conv_mfma<256, 8, 1, 4, false, 4><<<dim3(16, 1, 12), 256, 0, stream>>>(
      Bb, WF(7), nullptr, 8, 8, 256, nullptr, nullptr, nullptr, 0, pK, E8);
  reduce_stats<<<256, 256, 0, stream>>>(pK, A, E8, 12, 4, part);
  fin(7, 256, 256, 256, 1024);

  // ---- head ----
  head_mean<<<dim3(2, 4), 256, 0, stream>>>(A, SC(7), SH(7), hbuf);
  head_mv<<<dim3(2, 4), 256, 0, stream>>>(hbuf, wl, bl, (float*)d_out);
}

// Round 13
// 547.724 us; speedup vs baseline: 1.3309x; 1.0560x over previous
//
#include <hip/hip_runtime.h>

// ---------------------------------------------------------------------------
// VGG16-3D forward. R12: consolidation of measured-best config.
//   conv2/3/4: R6-style conv_mfma (pad-RB, direct reg-staged BN, no swizzle,
//   no setprio, no async) - best measured end-to-end (R6 = 563us).
//   conv1: K-packed (4 taps x 8ci -> 7 K-steps). Split-K stage 3/4.
//   DMA+bnpad path (R11) dropped: net -17+22 = +5us loss.
// ---------------------------------------------------------------------------

typedef _Float16 f16;
typedef _Float16 f16x8 __attribute__((ext_vector_type(8)));
typedef _Float16 f16x4 __attribute__((ext_vector_type(4)));
typedef float f32x4 __attribute__((ext_vector_type(4)));

__device__ __forceinline__ int xcd_swz(int bx, int nbx) {
  const int q = nbx >> 3, r = nbx & 7;
  const int x = bx & 7, o = bx >> 3;
  return (x < r ? x * (q + 1) : r * (q + 1) + (x - r) * q) + o;
}

// ---------------- fused weight prep (all 8 layers, one launch) --------------
// layers 1..7: [t][s][g][lane][i]; k = s*32 + (lane>>4)*8 + i, co = g*16+(lane&15)
// layer 0 (packed): k in [0,224): tap = k>>3 (27 real), ci = k&7 (3 real)
struct WArgs {
  const float* src[8];
  int end[8];
  int S[8], G[8], CR[8], CO[8];
};
__global__ __launch_bounds__(256) void wprep_all(WArgs a, f16* __restrict__ wf)
{
  const int e = blockIdx.x * 256 + threadIdx.x;
  int li = 0;
  while (li < 7 && e >= a.end[li]) ++li;
  if (e >= a.end[li]) return;
  const int base = li ? a.end[li - 1] : 0;
  int x = e - base;
  const int i = x & 7;
  const int l = (x >> 3) & 63;
  int r = x >> 9;
  const int g = r % a.G[li]; r /= a.G[li];
  const int s = r % a.S[li]; r /= a.S[li];
  const int t = r;
  const int k = s * 32 + ((l >> 4) << 3) + i;
  const int co = g * 16 + (l & 15);
  float v;
  if (li == 0) {
    const int tap = k >> 3, ci = k & 7;
    v = (ci < 3 && tap < 27) ? a.src[0][((long)tap * 3 + ci) * 64 + co] : 0.f;
  } else {
    v = (k < a.CR[li]) ? a.src[li][((long)t * a.CR[li] + k) * a.CO[li] + co] : 0.f;
  }
  wf[e] = (f16)v;
}

// ---------------- conv1: 3ch->64, packed K (4 taps x 8ci), 7 K-steps -------
__global__ __launch_bounds__(256) void conv1_mfma(
    const float* __restrict__ xin, const f16* __restrict__ wf,
    f16* __restrict__ out, float* __restrict__ part)
{
  constexpr int Z = 64, Y = 64, X = 64, L = 4;
  constexpr int RB = 48;
  constexpr int SLAB = (L + 2) * (Z + 2) * RB;
  __shared__ __align__(16) char slab[3 * SLAB];
  __shared__ float sstat[4][2][64];

  const int tid = threadIdx.x;
  const int lane = tid & 63;
  const int wr = tid >> 6;

  const int bxs = xcd_swz(blockIdx.x, gridDim.x);
  const long vb = (long)bxs * 256;
  const int n = (int)(vb >> 18);
  const int rem = (int)(vb & 262143);
  const int x0 = rem >> 12;
  const int y0 = (rem >> 6) & 63;

  if (tid < 36) {
    const int s = tid / 12, pr = tid % 12;
    const int row = (pr >> 1) * (Z + 2) + (pr & 1) * (Z + 1);
    const f16x8 hz = {};
    *(f16x8*)(slab + s * SLAB + row * RB) = hz;
  }

  for (int rr2 = tid; rr2 < 3 * (L + 2) * Z; rr2 += 256) {
    const int s = rr2 / ((L + 2) * Z);
    const int rr = rr2 % ((L + 2) * Z);
    const int li = rr / Z, z = rr % Z;
    const int xs = x0 + s - 1, ys = y0 - 1 + li;
    f16x8 h = {};
    if (xs >= 0 && xs < X && ys >= 0 && ys < Y) {
      const float* p = xin + (((long)(n * X + xs) * Y + ys) * Z + z) * 3;
      h[0] = (f16)p[0]; h[1] = (f16)p[1]; h[2] = (f16)p[2];
    }
    *(f16x8*)(slab + s * SLAB + (li * (Z + 2) + 1 + z) * RB) = h;
  }

  int abase[4];
  #pragma unroll
  for (int r = 0; r < 4; ++r) {
    const int vl = wr * 64 + r * 16 + (lane & 15);
    abase[r] = ((vl >> 6) * (Z + 2) + (vl & 63)) * RB;
  }
  const int c = lane >> 4;
  int rofftab[7];
  #pragma unroll
  for (int j = 0; j < 7; ++j) {
    const int tap = 4 * j + c;
    if (tap < 27) {
      const int dx = tap / 9, dy = (tap / 3) % 3, dz = tap % 3;
      rofftab[j] = dx * SLAB + (dy * (Z + 2) + dz) * RB;
    } else {
      rofftab[j] = 0;
    }
  }

  f32x4 acc[4][4];
  const f32x4 fz = {0.f, 0.f, 0.f, 0.f};
  #pragma unroll
  for (int r = 0; r < 4; ++r)
    #pragma unroll
    for (int cc = 0; cc < 4; ++cc) acc[r][cc] = fz;

  __syncthreads();

  #pragma unroll
  for (int j = 0; j < 7; ++j) {
    f16x8 av[4];
    #pragma unroll
    for (int r = 0; r < 4; ++r)
      av[r] = *(const f16x8*)(slab + abase[r] + rofftab[j]);
    f16x8 bv[4];
    #pragma unroll
    for (int c2 = 0; c2 < 4; ++c2)
      bv[c2] = *(const f16x8*)((const char*)wf + ((j * 4 + c2) << 10) + (lane << 4));
    #pragma unroll
    for (int r = 0; r < 4; ++r)
      #pragma unroll
      for (int c2 = 0; c2 < 4; ++c2)
        acc[r][c2] = __builtin_amdgcn_mfma_f32_16x16x32_f16(av[r], bv[c2], acc[r][c2], 0, 0, 0);
  }

  const long vgbase = vb + wr * 64;
  #pragma unroll
  for (int r = 0; r < 4; ++r)
    #pragma unroll
    for (int cc = 0; cc < 4; ++cc)
      #pragma unroll
      for (int q = 0; q < 4; ++q) {
        const long vox = vgbase + r * 16 + ((lane >> 4) << 2) + q;
        const int co = cc * 16 + (lane & 15);
        out[vox * 64 + co] = (f16)acc[r][cc][q];
      }

  float s4[4], q4[4];
  #pragma unroll
  for (int cc = 0; cc < 4; ++cc) {
    float s = 0.f, q = 0.f;
    #pragma unroll
    for (int r = 0; r < 4; ++r)
      #pragma unroll
      for (int qd = 0; qd < 4; ++qd) {
        const float v = acc[r][cc][qd];
        s += v;
        q = fmaf(v, v, q);
      }
    s4[cc] = s; q4[cc] = q;
  }
  #pragma unroll
  for (int cc = 0; cc < 4; ++cc) {
    s4[cc] += __shfl_xor(s4[cc], 16);
    s4[cc] += __shfl_xor(s4[cc], 32);
    q4[cc] += __shfl_xor(q4[cc], 16);
    q4[cc] += __shfl_xor(q4[cc], 32);
  }
  if (lane < 16) {
    #pragma unroll
    for (int cc = 0; cc < 4; ++cc) {
      sstat[wr][0][cc * 16 + lane] = s4[cc];
      sstat[wr][1][cc * 16 + lane] = q4[cc];
    }
  }
  __syncthreads();
  for (int t = tid; t < 128; t += 256) {
    const int k = (t >> 6) & 1, ch = t & 63;
    float v = 0.f;
    #pragma unroll
    for (int w2 = 0; w2 < 4; ++w2) v += sstat[w2][k][ch];
    part[(long)bxs * 128 + k * 64 + ch] = v;
  }
}

// ---------------- implicit-GEMM conv3d (R6 config: pad-RB, direct stage) ---
template<int CIN, int Z, int WR, int WC, bool HASBN, int SS>
__global__ __launch_bounds__(WR*WC*64) void conv_mfma(
    const f16* __restrict__ xin, const f16* __restrict__ wf,
    f16* __restrict__ out, int X, int Y, int Co,
    const float* __restrict__ sc, const float* __restrict__ sh,
    float* __restrict__ part, int partBase,
    float* __restrict__ pout, long outE)
{
  constexpr int NTHR = WR * WC * 64;
  constexpr int L = 64 * WR / Z;
  constexpr int RB = (CIN + 8) * 2;       // +8 f16 pad (R6 config)
  constexpr int S = CIN / 32;
  constexpr int COW = 64 * WC;
  constexpr bool SPLIT = (SS > 0);
  __shared__ __align__(16) char slab[(L + 2) * (Z + 2) * RB];
  __shared__ float sstat[SPLIT ? 1 : WR * WC][2][64];

  const int tid = threadIdx.x;
  const int lane = tid & 63;
  const int wv = tid >> 6;
  const int wr = wv / WC, wc = wv % WC;

  const int bxs = xcd_swz(blockIdx.x, gridDim.x);
  const long vb = (long)bxs * (64 * WR);
  const int XYZ = X * Y * Z;
  const int n = (int)(vb / XYZ);
  const int rem = (int)(vb % XYZ);
  const int x0 = rem / (Y * Z);
  const int y0 = (rem % (Y * Z)) / Z;
  const int co0 = blockIdx.y * COW;
  const int Gtot = Co >> 4;
  const int g0 = (co0 >> 4) + wc * 4;

  int abase[4];
  #pragma unroll
  for (int r = 0; r < 4; ++r) {
    const int vl = wr * 64 + r * 16 + (lane & 15);
    abase[r] = ((vl / Z) * (Z + 2) + (vl % Z)) * RB + ((lane >> 4) << 4);
  }

  f32x4 acc[4][4];
  const f32x4 fz = {0.f, 0.f, 0.f, 0.f};
  #pragma unroll
  for (int r = 0; r < 4; ++r)
    #pragma unroll
    for (int c = 0; c < 4; ++c) acc[r][c] = fz;

  {
    const f16x8 hz = {};
    for (int e = tid * 8; e < (L + 2) * 2 * CIN; e += NTHR * 8) {
      const int pr = e / CIN, ci = e % CIN;
      const int row = (pr >> 1) * (Z + 2) + (pr & 1) * (Z + 1);
      *(f16x8*)(slab + row * RB + ci * 2) = hz;
    }
  }

  auto stage = [&](int dx) {
    const int xs = x0 + dx - 1;
    const bool xok = (xs >= 0) && (xs < X);
    const long gv0 = ((long)(n * X + xs) * Y + (y0 - 1)) * Z;
    constexpr int NE = (L + 2) * Z * CIN;
    for (int e = tid * 8; e < NE; e += NTHR * 8) {
      const int rr = e / CIN, ci = e % CIN;
      const int li = rr / Z, z = rr % Z;
      const int ys = y0 - 1 + li;
      f16x8 h = {};
      if (xok && ys >= 0 && ys < Y) {
        h = *(const f16x8*)(xin + (gv0 + rr) * CIN + ci);
        if constexpr (HASBN) {
          const float4 s0 = *(const float4*)(sc + ci);
          const float4 s1 = *(const float4*)(sc + ci + 4);
          const float4 h0 = *(const float4*)(sh + ci);
          const float4 h1 = *(const float4*)(sh + ci + 4);
          h[0] = (f16)fmaxf(fmaf((float)h[0], s0.x, h0.x), 0.f);
          h[1] = (f16)fmaxf(fmaf((float)h[1], s0.y, h0.y), 0.f);
          h[2] = (f16)fmaxf(fmaf((float)h[2], s0.z, h0.z), 0.f);
          h[3] = (f16)fmaxf(fmaf((float)h[3], s0.w, h0.w), 0.f);
          h[4] = (f16)fmaxf(fmaf((float)h[4], s1.x, h1.x), 0.f);
          h[5] = (f16)fmaxf(fmaf((float)h[5], s1.y, h1.y), 0.f);
          h[6] = (f16)fmaxf(fmaf((float)h[6], s1.z, h1.z), 0.f);
          h[7] = (f16)fmaxf(fmaf((float)h[7], s1.w, h1.w), 0.f);
        }
      }
      *(f16x8*)(slab + (li * (Z + 2) + 1 + z) * RB + ci * 2) = h;
    }
  };

  auto ktaps = [&](int dx, int s) {
    #pragma unroll
    for (int dy = 0; dy < 3; ++dy) {
      #pragma unroll
      for (int dzi = 0; dzi < 3; ++dzi) {
        f16x8 av[4];
        #pragma unroll
        for (int r = 0; r < 4; ++r)
          av[r] = *(const f16x8*)(slab + abase[r] + s * 64 + (dy * (Z + 2) + dzi) * RB);
        const int t = dx * 9 + dy * 3 + dzi;
        f16x8 bv[4];
        #pragma unroll
        for (int c = 0; c < 4; ++c)
          bv[c] = *(const f16x8*)((const char*)wf +
                    (((long)(t * S + s) * Gtot + g0 + c) << 10) + (lane << 4));
        #pragma unroll
        for (int r = 0; r < 4; ++r)
          #pragma unroll
          for (int c = 0; c < 4; ++c)
            acc[r][c] = __builtin_amdgcn_mfma_f32_16x16x32_f16(av[r], bv[c], acc[r][c], 0, 0, 0);
      }
    }
  };

  if constexpr (SPLIT) {
    constexpr int SCH = S / SS;
    const int zb = blockIdx.z;
    const int dx = zb / SS;
    const int s0 = (zb % SS) * SCH;
    stage(dx);
    __syncthreads();
    #pragma unroll
    for (int si = 0; si < SCH; ++si) ktaps(dx, s0 + si);
  } else {
    for (int dx = 0; dx < 3; ++dx) {
      __syncthreads();
      stage(dx);
      __syncthreads();
      for (int s = 0; s < S; ++s) ktaps(dx, s);
    }
  }

  const long vgbase = vb + wr * 64;
  const int cobase = co0 + wc * 64;
  if constexpr (SPLIT) {
    float* pb = pout + (long)blockIdx.z * outE;
    #pragma unroll
    for (int r = 0; r < 4; ++r)
      #pragma unroll
      for (int c = 0; c < 4; ++c)
        #pragma unroll
        for (int q = 0; q < 4; ++q) {
          const long vox = vgbase + r * 16 + ((lane >> 4) << 2) + q;
          const int co = cobase + c * 16 + (lane & 15);
          pb[vox * Co + co] = acc[r][c][q];
        }
    return;
  }

  #pragma unroll
  for (int r = 0; r < 4; ++r)
    #pragma unroll
    for (int c = 0; c < 4; ++c)
      #pragma unroll
      for (int q = 0; q < 4; ++q) {
        const long vox = vgbase + r * 16 + ((lane >> 4) << 2) + q;
        const int co = cobase + c * 16 + (lane & 15);
        out[vox * Co + co] = (f16)acc[r][c][q];
      }

  float s4[4], q4[4];
  #pragma unroll
  for (int c = 0; c < 4; ++c) {
    float s = 0.f, q = 0.f;
    #pragma unroll
    for (int r = 0; r < 4; ++r)
      #pragma unroll
      for (int qd = 0; qd < 4; ++qd) {
        const float v = acc[r][c][qd];
        s += v;
        q = fmaf(v, v, q);
      }
    s4[c] = s; q4[c] = q;
  }
  #pragma unroll
  for (int c = 0; c < 4; ++c) {
    s4[c] += __shfl_xor(s4[c], 16);
    s4[c] += __shfl_xor(s4[c], 32);
    q4[c] += __shfl_xor(q4[c], 16);
    q4[c] += __shfl_xor(q4[c], 32);
  }
  if (lane < 16) {
    #pragma unroll
    for (int c = 0; c < 4; ++c) {
      sstat[wv][0][c * 16 + lane] = s4[c];
      sstat[wv][1][c * 16 + lane] = q4[c];
    }
  }
  __syncthreads();
  const long entry = (long)blockIdx.y * gridDim.x + bxs + partBase;
  for (int t = tid; t < WC * 128; t += NTHR) {
    const int wcc = t >> 7, k = (t >> 6) & 1, ch = t & 63;
    float v = 0.f;
    #pragma unroll
    for (int wr2 = 0; wr2 < WR; ++wr2) v += sstat[wr2 * WC + wcc][k][ch];
    part[entry * (2 * COW) + k * COW + wcc * 64 + ch] = v;
  }
}

// ------- split-K reduce: sum KS f32 partials -> f16 out, stats partials ----
__global__ __launch_bounds__(256) void reduce_stats(
    const float* __restrict__ pout, f16* __restrict__ out,
    long outE, int KS, int vpb, float* __restrict__ part)
{
  const int tid = threadIdx.x;
  const int wv = tid >> 6, lane = tid & 63;
  const int vbase = blockIdx.x * vpb;
  float4 s = {0.f, 0.f, 0.f, 0.f}, q = {0.f, 0.f, 0.f, 0.f};
  for (int v = vbase + wv; v < vbase + vpb; v += 4) {
    const long e = (long)v * 256 + lane * 4;
    float4 o = *(const float4*)(pout + e);
    for (int z = 1; z < KS; ++z) {
      const float4 p = *(const float4*)(pout + (long)z * outE + e);
      o.x += p.x; o.y += p.y; o.z += p.z; o.w += p.w;
    }
    f16x4 ov = {(f16)o.x, (f16)o.y, (f16)o.z, (f16)o.w};
    *(f16x4*)(out + e) = ov;
    s.x += o.x; s.y += o.y; s.z += o.z; s.w += o.w;
    q.x = fmaf(o.x, o.x, q.x); q.y = fmaf(o.y, o.y, q.y);
    q.z = fmaf(o.z, o.z, q.z); q.w = fmaf(o.w, o.w, q.w);
  }
  __shared__ float st[4][2][256];
  *(float4*)&st[wv][0][lane * 4] = s;
  *(float4*)&st[wv][1][lane * 4] = q;
  __syncthreads();
  for (int t = tid; t < 512; t += 256) {
    const int k = t >> 8, ch = t & 255;
    part[(long)blockIdx.x * 512 + k * 256 + ch] =
        st[0][k][ch] + st[1][k][ch] + st[2][k][ch] + st[3][k][ch];
  }
}

// ------- finalize: per-channel scale/shift from block partials -------------
__global__ __launch_bounds__(256) void stats_final(
    const float* __restrict__ part, int nbx, int CoWin, long nvox,
    const float* __restrict__ g, const float* __restrict__ b,
    float* __restrict__ sc, float* __restrict__ sh)
{
  const int c = blockIdx.x;
  const int by = c / CoWin;
  const int cw = c % CoWin;
  const int tid = threadIdx.x;
  float s = 0.f, ss = 0.f;
  for (int i = tid; i < nbx; i += 256) {
    const long base = ((long)by * nbx + i) * 2 * CoWin;
    s += part[base + cw];
    ss += part[base + CoWin + cw];
  }
  __shared__ float r0[256];
  __shared__ float r1[256];
  r0[tid] = s; r1[tid] = ss;
  __syncthreads();
  #pragma unroll
  for (int o = 128; o > 0; o >>= 1) {
    if (tid < o) { r0[tid] += r0[tid + o]; r1[tid] += r1[tid + o]; }
    __syncthreads();
  }
  if (tid == 0) {
    const float inv = 1.f / (float)nvox;
    const float m = r0[0] * inv;
    const float var = r1[0] * inv - m * m;
    const float scale = rsqrtf(var + 1e-5f) * g[c];
    sc[c] = scale;
    sh[c] = b[c] - m * scale;
  }
}

// maxpool(relu(bn(x))) == relu(bn(maxpool(x))) since bn scale > 0 here.
__global__ __launch_bounds__(256) void maxpool2_aff(
    const f16* __restrict__ in, f16* __restrict__ out,
    int N, int X, int Y, int Z, int C,
    const float* __restrict__ sc, const float* __restrict__ sh)
{
  const int OX = X >> 1, OY = Y >> 1, OZ = Z >> 1;
  const int c4n = C >> 2;
  const long nout = (long)N * OX * OY * OZ * c4n;
  long idx = (long)blockIdx.x * 256 + threadIdx.x;
  if (idx >= nout) return;
  const int c4 = (int)(idx % c4n);
  long v = idx / c4n;
  const int oz = (int)(v % OZ); v /= OZ;
  const int oy = (int)(v % OY); v /= OY;
  const int ox = (int)(v % OX);
  const int n = (int)(v / OX);
  const long sx = (long)Y * Z * C, sy = (long)Z * C, sz = C;
  const long base = ((((long)n * X + 2 * ox) * Y + 2 * oy) * Z + 2 * oz) * (long)C + 4L * c4;
  f16x4 m = *(const f16x4*)(in + base);
  #pragma unroll
  for (int dd = 1; dd < 8; ++dd) {
    const int dxp = dd >> 2, dyp = (dd >> 1) & 1, dzp = dd & 1;
    const f16x4 t = *(const f16x4*)(in + base + dxp * sx + dyp * sy + dzp * sz);
    #pragma unroll
    for (int i = 0; i < 4; ++i) m[i] = (t[i] > m[i]) ? t[i] : m[i];
  }
  const int c = 4 * c4;
  const float4 s4 = *(const float4*)(sc + c);
  const float4 h4 = *(const float4*)(sh + c);
  f16x4 r;
  r[0] = (f16)fmaxf(fmaf((float)m[0], s4.x, h4.x), 0.f);
  r[1] = (f16)fmaxf(fmaf((float)m[1], s4.y, h4.y), 0.f);
  r[2] = (f16)fmaxf(fmaf((float)m[2], s4.z, h4.z), 0.f);
  r[3] = (f16)fmaxf(fmaf((float)m[3], s4.w, h4.w), 0.f);
  *(f16x4*)(out + idx * 4) = r;
}

// ---- head stage A: BN8-affine(mean over 512 vox) -> hbuf[2][256] ----------
__global__ __launch_bounds__(256) void head_mean(
    const f16* __restrict__ x8, const float* __restrict__ sc, const float* __restrict__ sh,
    float* __restrict__ hbuf)
{
  const int n = blockIdx.x, cg = blockIdx.y;
  const int tx = threadIdx.x & 63, ty = threadIdx.x >> 6;
  const int c = cg * 64 + tx;
  float s = 0.f;
  for (int v = ty; v < 512; v += 4) s += (float)x8[((long)n * 512 + v) * 256 + c];
  __shared__ float red[4][64];
  red[ty][tx] = s;
  __syncthreads();
  if (ty == 0) {
    s = red[0][tx] + red[1][tx] + red[2][tx] + red[3][tx];
    hbuf[n * 256 + c] = fmaf(s * (1.f / 512.f), sc[c], sh[c]);
  }
}

// ---- head stage B: out = hbuf @ wl + bl ------------------------------------
__global__ __launch_bounds__(256) void head_mv(
    const float* __restrict__ hbuf, const float* __restrict__ wl,
    const float* __restrict__ bl, float* __restrict__ out)
{
  const int n = blockIdx.x, og = blockIdx.y;
  const int tx = threadIdx.x & 63, ty = threadIdx.x >> 6;
  const int oc = og * 64 + tx;
  float a = 0.f;
  const int k0 = ty * 64;
  for (int k = k0; k < k0 + 64; ++k)
    a = fmaf(hbuf[n * 256 + k], wl[(long)k * 256 + oc], a);
  __shared__ float red[4][64];
  red[ty][tx] = a;
  __syncthreads();
  if (ty == 0)
    out[n * 256 + oc] = red[0][tx] + red[1][tx] + red[2][tx] + red[3][tx] + bl[oc];
}

// ---------------------------------------------------------------------------
extern "C" void kernel_launch(void* const* d_in, const int* in_sizes, int n_in,
                              void* d_out, int out_size, void* d_ws, size_t ws_size,
                              hipStream_t stream)
{
  const float* x = (const float*)d_in[0];
  const float* W[8];
  const float* G[8];
  const float* B[8];
  for (int i = 0; i < 8; ++i) {
    W[i] = (const float*)d_in[1 + 3 * i];
    G[i] = (const float*)d_in[2 + 3 * i];
    B[i] = (const float*)d_in[3 + 3 * i];
  }
  const float* wl = (const float*)d_in[25];
  const float* bl = (const float*)d_in[26];

  // workspace carve-up
  char* ws = (char*)d_ws;
  f16*   A    = (f16*)ws;                          // 33,554,432 f16 (64 MiB)
  f16*   Bb   = (f16*)(ws + (64L << 20));          // 33,554,432 f16 (64 MiB)
  float* pK   = (float*)(ws + (128L << 20));       // 6,291,456 f32 (24 MiB)
  float* part = (float*)(ws + (152L << 20));       // 262,144 f32 (1 MiB)
  float* scb  = part + 262144L;                    // 8*256
  float* shb  = scb + 2048L;                       // 8*256
  float* hbuf = shb + 2048L;                       // 512
  f16*   wfb  = (f16*)(hbuf + 512L);               // packed weights ~14 MiB

  const int wfS[8]  = {7, 2, 2, 4, 4, 8, 8, 8};
  const int wfG[8]  = {4, 4, 8, 8, 16, 16, 16, 16};
  const int wfT[8]  = {1, 27, 27, 27, 27, 27, 27, 27};
  const int wfCR[8] = {3, 64, 64, 128, 128, 256, 256, 256};
  const int wfCO[8] = {64, 64, 128, 128, 256, 256, 256, 256};
  long wfOff[9];
  wfOff[0] = 0;
  for (int i = 0; i < 8; ++i) wfOff[i + 1] = wfOff[i] + (long)wfT[i] * wfS[i] * wfG[i] * 512;
  if (ws_size < (size_t)((char*)(wfb + wfOff[8]) - ws)) return;  // fail loud
  auto WF = [&](int i) { return wfb + wfOff[i]; };
  auto SC = [&](int i) { return scb + i * 256; };
  auto SH = [&](int i) { return shb + i * 256; };

  // ---- weight prep: one launch ----
  {
    WArgs a;
    for (int i = 0; i < 8; ++i) {
      a.src[i] = W[i]; a.end[i] = (int)wfOff[i + 1];
      a.S[i] = wfS[i]; a.G[i] = wfG[i]; a.CR[i] = wfCR[i]; a.CO[i] = wfCO[i];
    }
    wprep_all<<<(unsigned)((wfOff[8] + 255) / 256), 256, 0, stream>>>(a, wfb);
  }

  auto fin = [&](int layer, int nbx, int CoWin, int C, long nvox) {
    stats_final<<<C, 256, 0, stream>>>(part, nbx, CoWin, nvox,
                                       G[layer], B[layer], SC(layer), SH(layer));
  };
  auto pool_aff = [&](const f16* in, f16* ob, int N, int Xd, int Yd, int Zd, int C, int layer) {
    const long nout = (long)N * (Xd / 2) * (Yd / 2) * (Zd / 2) * (C / 4);
    maxpool2_aff<<<(unsigned)((nout + 255) / 256), 256, 0, stream>>>(
        in, ob, N, Xd, Yd, Zd, C, SC(layer), SH(layer));
  };

  // ---- stage 1: 64^3 ----
  conv1_mfma<<<2048, 256, 0, stream>>>(x, WF(0), A, part);
  fin(0, 2048, 64, 64, 524288);
  conv_mfma<64, 64, 4, 1, true, 0><<<dim3(2048, 1), 256, 0, stream>>>(
      A, WF(1), Bb, 64, 64, 64, SC(0), SH(0), part, 0, nullptr, 0);
  fin(1, 2048, 64, 64, 524288);
  pool_aff(Bb, A, 2, 64, 64, 64, 64, 1);          // P = A[0:4M]

  // ---- stage 2: 32^3 ----
  conv_mfma<64, 32, 2, 2, false, 0><<<dim3(512, 1), 256, 0, stream>>>(
      A, WF(2), Bb, 32, 32, 128, nullptr, nullptr, part, 0, nullptr, 0);
  fin(2, 512, 128, 128, 65536);
  conv_mfma<128, 32, 2, 2, true, 0><<<dim3(512, 1), 256, 0, stream>>>(
      Bb, WF(3), A, 32, 32, 128, SC(2), SH(2), part, 0, nullptr, 0);
  fin(3, 512, 128, 128, 65536);
  pool_aff(A, Bb, 2, 32, 32, 32, 128, 3);         // Q = Bb[0:1M]

  // ---- stage 3: 16^3, split-K (KS=3 over dx) ----
  const long E16 = 2097152;                        // 8192 vox * 256 ch
  conv_mfma<128, 16, 1, 4, false, 1><<<dim3(128, 1, 3), 256, 0, stream>>>(
      Bb, WF(4), nullptr, 16, 16, 256, nullptr, nullptr, nullptr, 0, pK, E16);
  reduce_stats<<<256, 256, 0, stream>>>(pK, A, E16, 3, 32, part);
  fin(4, 256, 256, 256, 8192);
  conv_mfma<256, 16, 1, 4, true, 1><<<dim3(128, 1, 3), 256, 0, stream>>>(
      A, WF(5), nullptr, 16, 16, 256, SC(4), SH(4), nullptr, 0, pK, E16);
  reduce_stats<<<256, 256, 0, stream>>>(pK, Bb, E16, 3, 32, part);
  fin(5, 256, 256, 256, 8192);
  conv_mfma<256, 16, 1, 4, true, 1><<<dim3(128, 1, 3), 256, 0, stream>>>(
      Bb, WF(6), nullptr, 16, 16, 256, SC(5), SH(5), nullptr, 0, pK, E16);
  reduce_stats<<<256, 256, 0, stream>>>(pK, A, E16, 3, 32, part);
  fin(6, 256, 256, 256, 8192);
  pool_aff(A, Bb, 2, 16, 16, 16, 256, 6);         // R = Bb[0:256K]

  // ---- stage 4: 8^3, split-K KS=12 ----
  const long E8 = 262144;
  conv_mfma<256, 8, 1, 4, false, 4><<<dim3(16, 1, 12), 256, 0, stream>>>(
      Bb, WF(7), nullptr, 8, 8, 256, nullptr, nullptr, nullptr, 0, pK, E8);
  reduce_stats<<<256, 256, 0, stream>>>(pK, A, E8, 12, 4, part);
  fin(7, 256, 256, 256, 1024);

  // ---- head ----
  head_mean<<<dim3(2, 4), 256, 0, stream>>>(A, SC(7), SH(7), hbuf);
  head_mv<<<dim3(2, 4), 256, 0, stream>>>(hbuf, wl, bl, (float*)d_out);
}